// Round 10
// baseline (536.096 us; speedup 1.0000x reference)
//
#include <hip/hip_runtime.h>

// PolicyHead fused kernel, R12.
// R11 post-mortem: on-demand LDS A-reads inflated transient live ranges ->
// 53MB spills, 206us. The 128-arch wall defeats every deep-prefetch variant.
// Law (R8/R9): time ~ linear in PER-WAVE serial stall points (~1.2us/pt).
// R12: halve points by splitting column-wise across 2x waves:
//  - 512 threads, 8 waves = 4 row-groups x 2 col-halves, still 2 batches.
//  - L1 and q2: each wave computes its 16-row x 128-col half -> 64 weight
//    loads/layer/wave -> 32 stall points total (was 64). Same per-CU weight
//    traffic (2-batch sharing kept), same 2 waves/SIMD (1 blk/CU x 8 waves).
//  - q2 materialized to a second 64KB LDS buffer; logits (K=256) read q2 +
//    out from LDS per col-half, zero weight loads.
//  - every phase's live set <= ~120 arch regs: no spills by construction.
// LDS = out 64K + q2 64K + 1.3K = 132KB (gfx950 limit 160KB), 1 block/CU.

typedef __bf16 bf16_t;
typedef __bf16 bf16x8 __attribute__((ext_vector_type(8)));
typedef float  f32x4  __attribute__((ext_vector_type(4)));

#define PSCALE 0.0625f
#define NPOL   1858
#define MFMA(a,b,c) __builtin_amdgcn_mfma_f32_16x16x32_bf16(a, b, c, 0, 0, 0)

// ---------------- prep kernels (ws path) ----------------
// ws layout: [0,128K) wfA = w1 frags bf16; [128K,256K) wfM = M frags bf16;
// [256K..) float region: c2[256] | v[256] | w4p[4][256] | pb[4] | s0.

__global__ void prep_w1(const float* __restrict__ w1, bf16_t* __restrict__ wfA) {
    int i = blockIdx.x * 256 + threadIdx.x;      // 0..65535
    int j = i & 7, lane = (i >> 3) & 63, t = (i >> 9) & 7, n = (i >> 12) & 15;
    int row = n * 16 + (lane & 15);              // output-col (w1 row)
    int col = t * 32 + (lane >> 4) * 8 + j;      // k index
    wfA[i] = (bf16_t)w1[row * 256 + col];
}

// M[m1][m2] = sum_h w2[h][m1]*w3[h][m2], written directly in B-frag layout
// for q2 = out @ M (frag elem = M[t*32+quad*8+j][n*16+l15]).
__global__ void prep_mat(const float* __restrict__ w2,
                         const float* __restrict__ w3,
                         bf16_t* __restrict__ wfM) {
    int m1 = blockIdx.x, m2 = threadIdx.x;
    float acc = 0.f;
    #pragma unroll 8
    for (int h = 0; h < 256; ++h)
        acc += w2[h * 256 + m1] * w3[h * 256 + m2];
    int t = m1 >> 5, quad = (m1 >> 3) & 3, j = m1 & 7;
    int n = m2 >> 4, l15 = m2 & 15;
    wfM[(((n * 8 + t) * 64) + (quad * 16 + l15)) * 8 + j] = (bf16_t)acc;
}

__global__ void prep_vecs(const float* __restrict__ w2,
                          const float* __restrict__ w3,
                          const float* __restrict__ b2,
                          const float* __restrict__ b3,
                          const float* __restrict__ w4,
                          float* __restrict__ flt) {
    int m = threadIdx.x;
    float c2 = 0.f, vv = 0.f, p0 = 0.f, p1 = 0.f, p2 = 0.f, p3 = 0.f;
    for (int h = 0; h < 256; ++h) {
        float w3h = w3[h * 256 + m];
        c2 += b2[h] * w3h;
        p0 += w4[h] * w3h;
        p1 += w4[256 + h] * w3h;
        p2 += w4[512 + h] * w3h;
        p3 += w4[768 + h] * w3h;
        vv += w2[h * 256 + m] * b3[h];
    }
    flt[m]        = c2;                          // c2[m]
    flt[256 + m]  = vv;                          // v[m]
    flt[512 + m]  = p0;                          // w4p[0][m]
    flt[768 + m]  = p1;
    flt[1024 + m] = p2;
    flt[1280 + m] = p3;
    if (m < 4) {
        float pb = 0.f;
        for (int h = 0; h < 256; ++h) pb += w4[m * 256 + h] * b3[h];
        flt[1536 + m] = pb;                      // pb[p]
    }
    if (m == 0) {
        float s = 0.f;
        for (int h = 0; h < 256; ++h) s += b2[h] * b3[h];
        flt[1540] = s;                           // s0
    }
}

// ---------------- shared device helpers ----------------

template <bool USE_WS>
__device__ __forceinline__ bf16x8 wfrag(const bf16_t* __restrict__ wl,
                                        const float* __restrict__ w,
                                        int n, int t, int lane) {
    if constexpr (USE_WS) {
        return *(const bf16x8*)(wl + (((n * 8 + t) * 64 + lane) << 3));
    } else {
        int l15 = lane & 15, quad = lane >> 4;
        const float* p = w + (n * 16 + l15) * 256 + t * 32 + quad * 8;
        f32x4 lo = *(const f32x4*)p;
        f32x4 hi = *(const f32x4*)(p + 4);
        bf16x8 v;
        v[0] = (bf16_t)lo[0]; v[1] = (bf16_t)lo[1];
        v[2] = (bf16_t)lo[2]; v[3] = (bf16_t)lo[3];
        v[4] = (bf16_t)hi[0]; v[5] = (bf16_t)hi[1];
        v[6] = (bf16_t)hi[2]; v[7] = (bf16_t)hi[3];
        return v;
    }
}

// Swizzled byte offset into a 64x256 bf16 buffer (32768 B).
__device__ __forceinline__ int ks_off(int row, int col) {
    return ((row << 9) + (col << 1)) ^ ((row & 7) << 4);
}

__device__ __forceinline__ bf16x8 cvt8(const float* __restrict__ p) {
    f32x4 lo = *(const f32x4*)p;
    f32x4 hi = *(const f32x4*)(p + 4);
    bf16x8 v;
    v[0] = (bf16_t)lo[0]; v[1] = (bf16_t)lo[1];
    v[2] = (bf16_t)lo[2]; v[3] = (bf16_t)lo[3];
    v[4] = (bf16_t)hi[0]; v[5] = (bf16_t)hi[1];
    v[6] = (bf16_t)hi[2]; v[7] = (bf16_t)hi[3];
    return v;
}

// 8 output tiles [nb, nb+8) x 16 rows, both batches, half-tile prefetch.
// 16 stall points per call (2 per tile).
template <bool RELU>
__device__ __forceinline__ void layer_half8(const bf16x8* inA, const bf16x8* inB,
                                            const bf16_t* __restrict__ wl,
                                            const float* __restrict__ bias,
                                            unsigned char* __restrict__ dst,
                                            int nb, int lane,
                                            int quad, int l15, int R) {
    bf16x8 wA[4], wB[4];
    #pragma unroll
    for (int t = 0; t < 4; ++t)
        wA[t] = wfrag<true>(wl, nullptr, nb, t, lane);

    #pragma unroll
    for (int k = 0; k < 8; ++k) {
        const int n = nb + k;
        #pragma unroll
        for (int t = 0; t < 4; ++t)
            wB[t] = wfrag<true>(wl, nullptr, n, 4 + t, lane);

        f32x4 aA0 = {0.f,0.f,0.f,0.f}, aA1 = {0.f,0.f,0.f,0.f};
        f32x4 aB0 = {0.f,0.f,0.f,0.f}, aB1 = {0.f,0.f,0.f,0.f};
        aA0 = MFMA(inA[0], wA[0], aA0);  aB0 = MFMA(inB[0], wA[0], aB0);
        aA1 = MFMA(inA[1], wA[1], aA1);  aB1 = MFMA(inB[1], wA[1], aB1);
        aA0 = MFMA(inA[2], wA[2], aA0);  aB0 = MFMA(inB[2], wA[2], aB0);
        aA1 = MFMA(inA[3], wA[3], aA1);  aB1 = MFMA(inB[3], wA[3], aB1);

        if (k < 7) {
            #pragma unroll
            for (int t = 0; t < 4; ++t)
                wA[t] = wfrag<true>(wl, nullptr, n + 1, t, lane);
        }

        aA0 = MFMA(inA[4], wB[0], aA0);  aB0 = MFMA(inB[4], wB[0], aB0);
        aA1 = MFMA(inA[5], wB[1], aA1);  aB1 = MFMA(inB[5], wB[1], aB1);
        aA0 = MFMA(inA[6], wB[2], aA0);  aB0 = MFMA(inB[6], wB[2], aB0);
        aA1 = MFMA(inA[7], wB[3], aA1);  aB1 = MFMA(inB[7], wB[3], aB1);

        f32x4 sA = aA0 + aA1, sB = aB0 + aB1;
        float bv = bias[n * 16 + l15];
        #pragma unroll
        for (int r2 = 0; r2 < 4; ++r2) {
            int off = ks_off(R + quad * 4 + r2, n * 16 + l15);
            float vA = sA[r2] + bv, vB = sB[r2] + bv;
            if (RELU) { vA = fmaxf(vA, 0.f); vB = fmaxf(vB, 0.f); }
            *(bf16_t*)(dst + off)         = (bf16_t)vA;
            *(bf16_t*)(dst + 32768 + off) = (bf16_t)vB;
        }
    }
}

// ---------------- R12 main kernel (ws path): 512 threads ----------------
__global__ __launch_bounds__(512, 2)
void policy_fused8(const float* __restrict__ x,
                   const bf16_t* __restrict__ wfA,
                   const bf16_t* __restrict__ wfM,
                   const float* __restrict__ flt,   // c2|v|w4p|pb|s0
                   const float* __restrict__ b1,
                   const int*   __restrict__ gidx,
                   float* __restrict__ out,
                   int nbat) {
    // u_lds: out (64x256 bf16 swizzled) x2 batches; later aliased as fullbuf.
    // q2b : q2  (64x256 bf16 swizzled) x2 batches.
    __shared__ __align__(16) unsigned char u_lds[65536];
    __shared__ __align__(16) unsigned char q2b[65536];
    __shared__ float promoLDS[2][4][8];
    __shared__ float patchLDS[2][8][8];
    __shared__ float qbLDS[2][64];

    const int tid  = threadIdx.x;
    const int lane = tid & 63;
    const int wv   = tid >> 6;        // 0..7
    const int rg   = wv >> 1;         // row group 0..3
    const int ch   = wv & 1;          // col half 0..1
    const int quad = lane >> 4;
    const int l15  = lane & 15;
    const int R    = rg * 16;         // row base
    const int NB   = ch * 8;          // col-tile base

    const int bat0 = blockIdx.x * 2;
    const bool has1 = (bat0 + 1) < nbat;
    const int bat1 = has1 ? bat0 + 1 : bat0;

    // ---- x A-fragments (rows R..R+15, full K), both batches ----
    bf16x8 xaA[8], xaB[8];
    {
        const float* xr0 = x + ((size_t)bat0 * 64 + R + l15) * 256;
        const float* xr1 = x + ((size_t)bat1 * 64 + R + l15) * 256;
        #pragma unroll
        for (int t = 0; t < 8; ++t) {
            xaA[t] = cvt8(xr0 + t * 32 + quad * 8);
            xaB[t] = cvt8(xr1 + t * 32 + quad * 8);
        }
    }

    // ---------------- layer 1 (col-half): out = relu(x@w1.T + b1) -----------
    layer_half8<true>(xaA, xaB, wfA, b1, u_lds, NB, lane, quad, l15, R);

    __syncthreads();   // #1: out complete

    // ---- oa readback (full K rows R..R+15) ----
    bf16x8 oaA[8], oaB[8];
    #pragma unroll
    for (int t = 0; t < 8; ++t) {
        int off = ks_off(R + l15, t * 32 + quad * 8);
        oaA[t] = *(const bf16x8*)(u_lds + off);
        oaB[t] = *(const bf16x8*)(u_lds + 32768 + off);
    }

    // ---------------- q2 (col-half) = out@M + c2 -> q2b ---------------------
    layer_half8<false>(oaA, oaB, wfM, flt, q2b, NB, lane, quad, l15, R);

    // ---- qb for batch=ch, rows R..R+15 (parked in LDS) ----
    {
        const bf16x8* oc = ch ? oaB : oaA;
        float qb = flt[1540];
        const float* vvec = flt + 256;
        #pragma unroll
        for (int t = 0; t < 8; ++t) {
            f32x4 va = *(const f32x4*)(vvec + t * 32 + quad * 8);
            f32x4 vb = *(const f32x4*)(vvec + t * 32 + quad * 8 + 4);
            qb += (float)oc[t][0]*va[0] + (float)oc[t][1]*va[1]
                + (float)oc[t][2]*va[2] + (float)oc[t][3]*va[3]
                + (float)oc[t][4]*vb[0] + (float)oc[t][5]*vb[1]
                + (float)oc[t][6]*vb[2] + (float)oc[t][7]*vb[3];
        }
        qb += __shfl_xor(qb, 16);
        qb += __shfl_xor(qb, 32);
        if (lane < 16) qbLDS[ch][R + lane] = qb;   // qb for row R+lane
    }

    __syncthreads();   // #2: q2b + qbLDS complete

    // ---- qa readback (full K rows R..R+15 of q2) ----
    bf16x8 qaA[8], qaB[8];
    #pragma unroll
    for (int t = 0; t < 8; ++t) {
        int off = ks_off(R + l15, t * 32 + quad * 8);
        qaA[t] = *(const bf16x8*)(q2b + off);
        qaB[t] = *(const bf16x8*)(q2b + 32768 + off);
    }

    // ---------------- logits (col-half): la = q2 @ out^T --------------------
    f32x4 laA[2], laB[2];
    laA[0] = (f32x4){0.f,0.f,0.f,0.f}; laA[1] = (f32x4){0.f,0.f,0.f,0.f};
    laB[0] = (f32x4){0.f,0.f,0.f,0.f}; laB[1] = (f32x4){0.f,0.f,0.f,0.f};
    #pragma unroll
    for (int t8 = 0; t8 < 8; ++t8) {
        #pragma unroll
        for (int npl = 0; npl < 2; ++npl) {
            int ko = ks_off((2 * ch + npl) * 16 + l15, t8 * 32 + quad * 8);
            bf16x8 kA = *(const bf16x8*)(u_lds + ko);
            bf16x8 kB = *(const bf16x8*)(u_lds + 32768 + ko);
            laA[npl] = MFMA(qaA[t8], kA, laA[npl]);
            laB[npl] = MFMA(qaB[t8], kB, laB[npl]);
        }
    }

    // ---------------- promo: wave handles p=rg, batch=ch --------------------
    {
        int s = lane >> 3, seg = lane & 7;
        const float* wrow = flt + 512 + rg * 256;
        const unsigned char* kb = u_lds + ch * 32768;
        float pacc = 0.f;
        #pragma unroll
        for (int m = 0; m < 4; ++m) {
            bf16x8 kv = *(const bf16x8*)(kb + ks_off(56 + s, seg * 32 + m * 8));
            f32x4 wa = *(const f32x4*)(wrow + seg * 32 + m * 8);
            f32x4 wb = *(const f32x4*)(wrow + seg * 32 + m * 8 + 4);
            pacc += (float)kv[0] * wa[0] + (float)kv[1] * wa[1]
                  + (float)kv[2] * wa[2] + (float)kv[3] * wa[3]
                  + (float)kv[4] * wb[0] + (float)kv[5] * wb[1]
                  + (float)kv[6] * wb[2] + (float)kv[7] * wb[3];
        }
        pacc += __shfl_down(pacc, 4);
        pacc += __shfl_down(pacc, 2);
        pacc += __shfl_down(pacc, 1);
        if (seg == 0) promoLDS[ch][rg][s] = pacc + flt[1536 + rg];
    }

    // ---- patch logits[48:56, 56:64]: rows 48-55 (rg=3,quad<2), cols 56-63
    //      (np=3 -> ch=1, npl=1) -> wave wv==7, both batches.
    if (wv == 7 && quad < 2 && l15 >= 8) {
        #pragma unroll
        for (int r2 = 0; r2 < 4; ++r2) {
            int row = 48 + quad * 4 + r2;
            patchLDS[0][quad * 4 + r2][l15 - 8] =
                (laA[1][r2] + qbLDS[0][row]) * PSCALE;
            patchLDS[1][quad * 4 + r2][l15 - 8] =
                (laB[1][r2] + qbLDS[1][row]) * PSCALE;
        }
    }

    __syncthreads();   // #3: all u_lds/q2b reads done; promo/patch staged

    // ---------------- fullbuf (aliased over out regions) --------------------
    float* fb0 = (float*)u_lds;
    float* fb1 = (float*)(u_lds + 32768);
    {
        float qb0[4], qb1[4];
        #pragma unroll
        for (int r2 = 0; r2 < 4; ++r2) {
            qb0[r2] = qbLDS[0][R + quad * 4 + r2];
            qb1[r2] = qbLDS[1][R + quad * 4 + r2];
        }
        #pragma unroll
        for (int npl = 0; npl < 2; ++npl) {
            #pragma unroll
            for (int r2 = 0; r2 < 4; ++r2) {
                int idx = (R + quad * 4 + r2) * 64 + (2 * ch + npl) * 16 + l15;
                fb0[idx] = (laA[npl][r2] + qb0[r2]) * PSCALE;
                fb1[idx] = (laB[npl][r2] + qb1[r2]) * PSCALE;
            }
        }
    }

    // promo rows 64..66, both batches (384 threads)
    if (tid < 384) {
        int b  = tid / 192;
        int m  = tid - b * 192;
        int u  = m >> 6, vv2 = m & 63;
        int mm = u * 64 + vv2;
        int r_ = mm / 24, c_ = mm - r_ * 24;
        int c3 = c_ / 3, cp = c_ - c3 * 3;
        float* fb = b ? fb1 : fb0;
        fb[(64 + u) * 64 + vv2] =
            promoLDS[b][cp][c3] + promoLDS[b][3][c3] + patchLDS[b][r_][c3];
    }

    __syncthreads();   // #4: fullbufs ready

    // ---------------- gather (512 threads x 4) ------------------------------
    {
        float* orow0 = out + (size_t)bat0 * NPOL;
        float* orow1 = out + (size_t)(bat0 + 1) * NPOL;
        int   idxv[4];
        float v0[4], v1[4];
        #pragma unroll
        for (int i = 0; i < 4; ++i) {
            int g = tid + i * 512;
            idxv[i] = (g < NPOL) ? gidx[g] : 0;
        }
        #pragma unroll
        for (int i = 0; i < 4; ++i) {
            v0[i] = fb0[idxv[i]];
            v1[i] = fb1[idxv[i]];
        }
        #pragma unroll
        for (int i = 0; i < 4; ++i) {
            int g = tid + i * 512;
            if (g < NPOL) {
                orow0[g] = v0[i];
                if (has1) orow1[g] = v1[i];
            }
        }
    }
}

// ---------------- fallback kernel (no-workspace path, R9 structure) ---------
__device__ __forceinline__ void mfma16f(const bf16x8* inA, const bf16x8* inB,
                                        const bf16x8* w, f32x4& s0, f32x4& s1) {
    f32x4 a00 = {0.f,0.f,0.f,0.f}, a01 = {0.f,0.f,0.f,0.f};
    f32x4 a10 = {0.f,0.f,0.f,0.f}, a11 = {0.f,0.f,0.f,0.f};
    #pragma unroll
    for (int t = 0; t < 8; t += 2) {
        a00 = MFMA(inA[t],     w[t],     a00);
        a10 = MFMA(inB[t],     w[t],     a10);
        a01 = MFMA(inA[t + 1], w[t + 1], a01);
        a11 = MFMA(inB[t + 1], w[t + 1], a11);
    }
    s0 = a00 + a01;
    s1 = a10 + a11;
}

template <bool RELU>
__device__ __forceinline__ void layer_raw(const bf16x8* inA, const bf16x8* inB,
                                          const float* __restrict__ wraw,
                                          const float* __restrict__ bias,
                                          unsigned char* __restrict__ u_lds,
                                          int lane, int quad, int l15, int R) {
    bf16x8 wA[4], wB[4];
    #pragma unroll
    for (int t = 0; t < 4; ++t)
        wA[t] = wfrag<false>(nullptr, wraw, 0, t, lane);
    #pragma unroll
    for (int n = 0; n < 16; ++n) {
        #pragma unroll
        for (int t = 0; t < 4; ++t)
            wB[t] = wfrag<false>(nullptr, wraw, n, 4 + t, lane);
        f32x4 aA0 = {0.f,0.f,0.f,0.f}, aA1 = {0.f,0.f,0.f,0.f};
        f32x4 aB0 = {0.f,0.f,0.f,0.f}, aB1 = {0.f,0.f,0.f,0.f};
        aA0 = MFMA(inA[0], wA[0], aA0);  aB0 = MFMA(inB[0], wA[0], aB0);
        aA1 = MFMA(inA[1], wA[1], aA1);  aB1 = MFMA(inB[1], wA[1], aB1);
        aA0 = MFMA(inA[2], wA[2], aA0);  aB0 = MFMA(inB[2], wA[2], aB0);
        aA1 = MFMA(inA[3], wA[3], aA1);  aB1 = MFMA(inB[3], wA[3], aB1);
        if (n < 15) {
            #pragma unroll
            for (int t = 0; t < 4; ++t)
                wA[t] = wfrag<false>(nullptr, wraw, n + 1, t, lane);
        }
        aA0 = MFMA(inA[4], wB[0], aA0);  aB0 = MFMA(inB[4], wB[0], aB0);
        aA1 = MFMA(inA[5], wB[1], aA1);  aB1 = MFMA(inB[5], wB[1], aB1);
        aA0 = MFMA(inA[6], wB[2], aA0);  aB0 = MFMA(inB[6], wB[2], aB0);
        aA1 = MFMA(inA[7], wB[3], aA1);  aB1 = MFMA(inB[7], wB[3], aB1);
        f32x4 sA = aA0 + aA1, sB = aB0 + aB1;
        float bv = bias[n * 16 + l15];
        #pragma unroll
        for (int r2 = 0; r2 < 4; ++r2) {
            int off = ks_off(R + quad * 4 + r2, n * 16 + l15);
            float vA = sA[r2] + bv, vB = sB[r2] + bv;
            if (RELU) { vA = fmaxf(vA, 0.f); vB = fmaxf(vB, 0.f); }
            *(bf16_t*)(u_lds + off)         = (bf16_t)vA;
            *(bf16_t*)(u_lds + 32768 + off) = (bf16_t)vB;
        }
    }
}

__global__ __launch_bounds__(256, 2)
void policy_main(const float* __restrict__ x,
                 const float* __restrict__ w1,
                 const float* __restrict__ w2,
                 const float* __restrict__ w3,
                 const float* __restrict__ b1,
                 const float* __restrict__ b2,
                 const float* __restrict__ b3,
                 const float* __restrict__ w4,
                 const int*   __restrict__ gidx,
                 float* __restrict__ out,
                 int nbat) {
    __shared__ __align__(16) unsigned char u_lds[2 * 32768];
    __shared__ __align__(16) bf16_t qscr[4][2][16 * 40];
    __shared__ float promoLDS[2][4][8];
    __shared__ float patchLDS[2][8][8];

    const int tid  = threadIdx.x;
    const int lane = tid & 63;
    const int wv   = tid >> 6;
    const int quad = lane >> 4;
    const int l15  = lane & 15;
    const int R    = wv * 16;

    const int bat0 = blockIdx.x * 2;
    const bool has1 = (bat0 + 1) < nbat;
    const int bat1 = has1 ? bat0 + 1 : bat0;

    bf16x8 xaA[8], xaB[8];
    {
        const float* xr0 = x + ((size_t)bat0 * 64 + R + l15) * 256;
        const float* xr1 = x + ((size_t)bat1 * 64 + R + l15) * 256;
        #pragma unroll
        for (int t = 0; t < 8; ++t) {
            xaA[t] = cvt8(xr0 + t * 32 + quad * 8);
            xaB[t] = cvt8(xr1 + t * 32 + quad * 8);
        }
    }

    layer_raw<true>(xaA, xaB, w1, b1, u_lds, lane, quad, l15, R);
    bf16x8 oaA[8], oaB[8];
    #pragma unroll
    for (int t = 0; t < 8; ++t) {
        int off = ks_off(R + l15, t * 32 + quad * 8);
        oaA[t] = *(const bf16x8*)(u_lds + off);
        oaB[t] = *(const bf16x8*)(u_lds + 32768 + off);
    }

    layer_raw<false>(oaA, oaB, w3, b3, u_lds, lane, quad, l15, R);

    __syncthreads();

    f32x4 laA[4], laB[4];
    #pragma unroll
    for (int n = 0; n < 4; ++n) {
        laA[n] = (f32x4){0.f,0.f,0.f,0.f};
        laB[n] = (f32x4){0.f,0.f,0.f,0.f};
    }
    {
        bf16_t* qsA = &qscr[wv][0][0];
        bf16_t* qsB = &qscr[wv][1][0];
        bf16x8 wA[4], wB[4];
        #pragma unroll
        for (int t = 0; t < 4; ++t)
            wA[t] = wfrag<false>(nullptr, w2, 0, t, lane);

        #pragma unroll
        for (int t8 = 0; t8 < 8; ++t8) {
            const int n0 = 2 * t8, n1 = n0 + 1;
            #pragma unroll
            for (int t = 0; t < 4; ++t)
                wB[t] = wfrag<false>(nullptr, w2, n0, 4 + t, lane);
            {
                f32x4 sA, sB;
                bf16x8 wfull[8] = {wA[0], wA[1], wA[2], wA[3],
                                   wB[0], wB[1], wB[2], wB[3]};
                mfma16f(oaA, oaB, wfull, sA, sB);
                float bv = b2[n0 * 16 + l15];
                #pragma unroll
                for (int r2 = 0; r2 < 4; ++r2) {
                    int qo = (quad * 4 + r2) * 40 + l15;
                    qsA[qo] = (bf16_t)(sA[r2] + bv);
                    qsB[qo] = (bf16_t)(sB[r2] + bv);
                }
            }
            #pragma unroll
            for (int t = 0; t < 4; ++t)
                wA[t] = wfrag<false>(nullptr, w2, n1, t, lane);
            #pragma unroll
            for (int t = 0; t < 4; ++t)
                wB[t] = wfrag<false>(nullptr, w2, n1, 4 + t, lane);
            {
                f32x4 sA, sB;
                bf16x8 wfull[8] = {wA[0], wA[1], wA[2], wA[3],
                                   wB[0], wB[1], wB[2], wB[3]};
                mfma16f(oaA, oaB, wfull, sA, sB);
                float bv = b2[n1 * 16 + l15];
                #pragma unroll
                for (int r2 = 0; r2 < 4; ++r2) {
                    int qo = (quad * 4 + r2) * 40 + 16 + l15;
                    qsA[qo] = (bf16_t)(sA[r2] + bv);
                    qsB[qo] = (bf16_t)(sB[r2] + bv);
                }
            }
            if (t8 < 7) {
                #pragma unroll
                for (int t = 0; t < 4; ++t)
                    wA[t] = wfrag<false>(nullptr, w2, n0 + 2, t, lane);
            }
            bf16x8 qaA = *(const bf16x8*)(qsA + l15 * 40 + quad * 8);
            bf16x8 qaB = *(const bf16x8*)(qsB + l15 * 40 + quad * 8);
            #pragma unroll
            for (int np = 0; np < 4; ++np) {
                int ko = ks_off(np * 16 + l15, t8 * 32 + quad * 8);
                bf16x8 kA = *(const bf16x8*)(u_lds + ko);
                bf16x8 kB = *(const bf16x8*)(u_lds + 32768 + ko);
                laA[np] = MFMA(qaA, kA, laA[np]);
                laB[np] = MFMA(qaB, kB, laB[np]);
            }
        }
    }

    {
        int s = lane >> 3, seg = lane & 7;
        const float* wrow = w4 + wv * 256;
        #pragma unroll
        for (int b = 0; b < 2; ++b) {
            const unsigned char* kb = u_lds + b * 32768;
            float p = 0.f;
            #pragma unroll
            for (int m = 0; m < 4; ++m) {
                bf16x8 kv = *(const bf16x8*)(kb + ks_off(56 + s, seg * 32 + m * 8));
                f32x4 wa = *(const f32x4*)(wrow + seg * 32 + m * 8);
                f32x4 wb = *(const f32x4*)(wrow + seg * 32 + m * 8 + 4);
                p += (float)kv[0] * wa[0] + (float)kv[1] * wa[1]
                   + (float)kv[2] * wa[2] + (float)kv[3] * wa[3]
                   + (float)kv[4] * wb[0] + (float)kv[5] * wb[1]
                   + (float)kv[6] * wb[2] + (float)kv[7] * wb[3];
            }
            p += __shfl_down(p, 4);
            p += __shfl_down(p, 2);
            p += __shfl_down(p, 1);
            if (seg == 0) promoLDS[b][wv][s] = p;
        }
    }

    if (wv == 3 && quad < 2 && l15 >= 8) {
        #pragma unroll
        for (int r2 = 0; r2 < 4; ++r2) {
            patchLDS[0][quad * 4 + r2][l15 - 8] = laA[3][r2] * PSCALE;
            patchLDS[1][quad * 4 + r2][l15 - 8] = laB[3][r2] * PSCALE;
        }
    }

    __syncthreads();

    float* fb0 = (float*)u_lds;
    float* fb1 = (float*)(u_lds + 32768);
    #pragma unroll
    for (int n = 0; n < 4; ++n) {
        #pragma unroll
        for (int r2 = 0; r2 < 4; ++r2) {
            int idx = (R + quad * 4 + r2) * 64 + n * 16 + l15;
            fb0[idx] = laA[n][r2] * PSCALE;
            fb1[idx] = laB[n][r2] * PSCALE;
        }
    }

    if (tid < 192) {
        int u = tid >> 6, vv2 = tid & 63;
        int mm = u * 64 + vv2;
        int r_ = mm / 24, c_ = mm - r_ * 24;
        int c3 = c_ / 3, cp = c_ - c3 * 3;
        fb0[(64 + u) * 64 + vv2] =
            promoLDS[0][cp][c3] + promoLDS[0][3][c3] + patchLDS[0][r_][c3];
        fb1[(64 + u) * 64 + vv2] =
            promoLDS[1][cp][c3] + promoLDS[1][3][c3] + patchLDS[1][r_][c3];
    }

    __syncthreads();

    {
        float* orow0 = out + (size_t)bat0 * NPOL;
        float* orow1 = out + (size_t)(bat0 + 1) * NPOL;
        int   idxv[8];
        float v0[8], v1[8];
        #pragma unroll
        for (int i = 0; i < 8; ++i) {
            int g = tid + i * 256;
            idxv[i] = (g < NPOL) ? gidx[g] : 0;
        }
        #pragma unroll
        for (int i = 0; i < 8; ++i) {
            v0[i] = fb0[idxv[i]];
            v1[i] = fb1[idxv[i]];
        }
        #pragma unroll
        for (int i = 0; i < 8; ++i) {
            int g = tid + i * 256;
            if (g < NPOL) {
                orow0[g] = v0[i];
                if (has1) orow1[g] = v1[i];
            }
        }
    }
}

extern "C" void kernel_launch(void* const* d_in, const int* in_sizes, int n_in,
                              void* d_out, int out_size, void* d_ws, size_t ws_size,
                              hipStream_t stream) {
    const float* x    = (const float*)d_in[0];
    const float* w1   = (const float*)d_in[1];
    const float* b1   = (const float*)d_in[2];
    const float* w2   = (const float*)d_in[3];
    const float* b2   = (const float*)d_in[4];
    const float* w3   = (const float*)d_in[5];
    const float* b3   = (const float*)d_in[6];
    const float* w4   = (const float*)d_in[7];
    const int*   gidx = (const int*)d_in[8];
    float* out = (float*)d_out;

    int nbat = in_sizes[0] / (64 * 256);        // 4096
    int nblk = (nbat + 1) / 2;
    const size_t ws_needed = 262144 + 8192;     // wfA+wfM (256K) + float region

    if (ws_size >= ws_needed) {
        bf16_t* wfA = (bf16_t*)d_ws;
        bf16_t* wfM = wfA + 65536;
        float*  flt = (float*)((char*)d_ws + 262144);
        prep_w1  <<<256, 256, 0, stream>>>(w1, wfA);
        prep_mat <<<256, 256, 0, stream>>>(w2, w3, wfM);
        prep_vecs<<<1,   256, 0, stream>>>(w2, w3, b2, b3, w4, flt);
        policy_fused8<<<nblk, 512, 0, stream>>>(
            x, wfA, wfM, flt, b1, gidx, out, nbat);
    } else {
        policy_main<<<nblk, 256, 0, stream>>>(
            x, w1, w2, w3, b1, b2, b3, w4, gidx, out, nbat);
    }
}

// Round 11
// 528.470 us; speedup vs baseline: 1.0144x; 1.0144x over previous
//
#include <hip/hip_runtime.h>

// PolicyHead fused kernel, R13.
// R12 post-mortem: halved stall points but lost inter-block independence
// (8-wave single block, lockstep barriers) -> 223us > R9's 185. Refined law:
// time ~ stall points / independent-stream diversity. R9 shape is right.
// R13 = R9 + LDS-staged layer-1 weights via global_load_lds:
//  - all 4 waves read IDENTICAL weight frags; stage each 8KB n-tile into LDS
//    once per block (async, ZERO register cost), waves ds_read_b128 from LDS.
//  - ring-2 of 4KB half-tiles lives in the qscr region (union: qscr is only
//    used in the fused phase) -> LDS stays 76.8KB, 2 blocks/CU preserved.
//  - 32 block barriers in L1 (one per half-tile) are the price; cheap with
//    2 independent blocks/CU.
//  - fused phase unchanged from R9 (qscr needed for q2 transpose there).

typedef __bf16 bf16_t;
typedef __bf16 bf16x8 __attribute__((ext_vector_type(8)));
typedef float  f32x4  __attribute__((ext_vector_type(4)));

#define PSCALE 0.0625f
#define NPOL   1858
#define MFMA(a,b,c) __builtin_amdgcn_mfma_f32_16x16x32_bf16(a, b, c, 0, 0, 0)

// ---------------- prep kernels (ws path) ----------------
// ws layout: [0,128K) wfA = w1 frags bf16; [128K,256K) wfM = M frags bf16;
// [256K..) float region: c2[256] | v[256] | w4p[4][256] | pb[4] | s0.

__global__ void prep_w1(const float* __restrict__ w1, bf16_t* __restrict__ wfA) {
    int i = blockIdx.x * 256 + threadIdx.x;      // 0..65535
    int j = i & 7, lane = (i >> 3) & 63, t = (i >> 9) & 7, n = (i >> 12) & 15;
    int row = n * 16 + (lane & 15);              // output-col (w1 row)
    int col = t * 32 + (lane >> 4) * 8 + j;      // k index
    wfA[i] = (bf16_t)w1[row * 256 + col];
}

// M[m1][m2] = sum_h w2[h][m1]*w3[h][m2], written directly in B-frag layout
// for q2 = out @ M (frag elem = M[t*32+quad*8+j][n*16+l15]).
__global__ void prep_mat(const float* __restrict__ w2,
                         const float* __restrict__ w3,
                         bf16_t* __restrict__ wfM) {
    int m1 = blockIdx.x, m2 = threadIdx.x;
    float acc = 0.f;
    #pragma unroll 8
    for (int h = 0; h < 256; ++h)
        acc += w2[h * 256 + m1] * w3[h * 256 + m2];
    int t = m1 >> 5, quad = (m1 >> 3) & 3, j = m1 & 7;
    int n = m2 >> 4, l15 = m2 & 15;
    wfM[(((n * 8 + t) * 64) + (quad * 16 + l15)) * 8 + j] = (bf16_t)acc;
}

__global__ void prep_vecs(const float* __restrict__ w2,
                          const float* __restrict__ w3,
                          const float* __restrict__ b2,
                          const float* __restrict__ b3,
                          const float* __restrict__ w4,
                          float* __restrict__ flt) {
    int m = threadIdx.x;
    float c2 = 0.f, vv = 0.f, p0 = 0.f, p1 = 0.f, p2 = 0.f, p3 = 0.f;
    for (int h = 0; h < 256; ++h) {
        float w3h = w3[h * 256 + m];
        c2 += b2[h] * w3h;
        p0 += w4[h] * w3h;
        p1 += w4[256 + h] * w3h;
        p2 += w4[512 + h] * w3h;
        p3 += w4[768 + h] * w3h;
        vv += w2[h * 256 + m] * b3[h];
    }
    flt[m]        = c2;                          // c2[m]
    flt[256 + m]  = vv;                          // v[m]
    flt[512 + m]  = p0;                          // w4p[0][m]
    flt[768 + m]  = p1;
    flt[1024 + m] = p2;
    flt[1280 + m] = p3;
    if (m < 4) {
        float pb = 0.f;
        for (int h = 0; h < 256; ++h) pb += w4[m * 256 + h] * b3[h];
        flt[1536 + m] = pb;                      // pb[p]
    }
    if (m == 0) {
        float s = 0.f;
        for (int h = 0; h < 256; ++h) s += b2[h] * b3[h];
        flt[1540] = s;                           // s0
    }
}

// ---------------- shared device helpers ----------------

template <bool USE_WS>
__device__ __forceinline__ bf16x8 wfrag(const bf16_t* __restrict__ wl,
                                        const float* __restrict__ w,
                                        int n, int t, int lane) {
    if constexpr (USE_WS) {
        return *(const bf16x8*)(wl + (((n * 8 + t) * 64 + lane) << 3));
    } else {
        int l15 = lane & 15, quad = lane >> 4;
        const float* p = w + (n * 16 + l15) * 256 + t * 32 + quad * 8;
        f32x4 lo = *(const f32x4*)p;
        f32x4 hi = *(const f32x4*)(p + 4);
        bf16x8 v;
        v[0] = (bf16_t)lo[0]; v[1] = (bf16_t)lo[1];
        v[2] = (bf16_t)lo[2]; v[3] = (bf16_t)lo[3];
        v[4] = (bf16_t)hi[0]; v[5] = (bf16_t)hi[1];
        v[6] = (bf16_t)hi[2]; v[7] = (bf16_t)hi[3];
        return v;
    }
}

// Swizzled byte offset into a 64x256 bf16 buffer (32768 B).
__device__ __forceinline__ int ks_off(int row, int col) {
    return ((row << 9) + (col << 1)) ^ ((row & 7) << 4);
}

__device__ __forceinline__ bf16x8 cvt8(const float* __restrict__ p) {
    f32x4 lo = *(const f32x4*)p;
    f32x4 hi = *(const f32x4*)(p + 4);
    bf16x8 v;
    v[0] = (bf16_t)lo[0]; v[1] = (bf16_t)lo[1];
    v[2] = (bf16_t)lo[2]; v[3] = (bf16_t)lo[3];
    v[4] = (bf16_t)hi[0]; v[5] = (bf16_t)hi[1];
    v[6] = (bf16_t)hi[2]; v[7] = (bf16_t)hi[3];
    return v;
}

// Async 16B/lane global->LDS (wave-uniform LDS base; HW scatters lane*16).
__device__ __forceinline__ void gload_lds16(const void* g, void* l) {
    __builtin_amdgcn_global_load_lds(
        (const __attribute__((address_space(1))) void*)g,
        (__attribute__((address_space(3))) void*)l, 16, 0, 0);
}

// Layer 1 with BLOCK-STAGED weights: ring-2 of 4KB half-tiles in wst.
// Wave wv stages 1KB of each half; all waves read frags from LDS.
template <bool RELU>
__device__ __forceinline__ void layer_staged(const bf16x8* inA, const bf16x8* inB,
                                             const bf16_t* __restrict__ wsrc,
                                             const float* __restrict__ bias,
                                             unsigned char* __restrict__ u_lds,
                                             unsigned char* __restrict__ wst,
                                             int wv, int lane,
                                             int quad, int l15, int R) {
    const unsigned char* wsb = (const unsigned char*)wsrc;
    // prologue: stage half 0 into slot 0
    gload_lds16(wsb + wv * 1024 + lane * 16, wst + wv * 1024);

    f32x4 aA0, aA1, aB0, aB1;
    #pragma unroll
    for (int h = 0; h < 32; ++h) {
        const int n = h >> 1, hb = h & 1;
        __syncthreads();   // stage h landed (vmcnt drain); reads of h-1 done
        if (h < 31) {
            const int h1 = h + 1;
            gload_lds16(wsb + (size_t)h1 * 4096 + wv * 1024 + lane * 16,
                        wst + (h1 & 1) * 4096 + wv * 1024);
        }
        const unsigned char* sb = wst + (h & 1) * 4096;
        bf16x8 w0 = *(const bf16x8*)(sb + 0 * 1024 + lane * 16);
        bf16x8 w1 = *(const bf16x8*)(sb + 1 * 1024 + lane * 16);
        bf16x8 w2 = *(const bf16x8*)(sb + 2 * 1024 + lane * 16);
        bf16x8 w3 = *(const bf16x8*)(sb + 3 * 1024 + lane * 16);
        if (hb == 0) {
            aA0 = (f32x4){0.f,0.f,0.f,0.f}; aA1 = aA0;
            aB0 = aA0; aB1 = aA0;
        }
        const bf16x8* iA = inA + hb * 4;
        const bf16x8* iB = inB + hb * 4;
        aA0 = MFMA(iA[0], w0, aA0);  aB0 = MFMA(iB[0], w0, aB0);
        aA1 = MFMA(iA[1], w1, aA1);  aB1 = MFMA(iB[1], w1, aB1);
        aA0 = MFMA(iA[2], w2, aA0);  aB0 = MFMA(iB[2], w2, aB0);
        aA1 = MFMA(iA[3], w3, aA1);  aB1 = MFMA(iB[3], w3, aB1);
        if (hb == 1) {
            f32x4 sA = aA0 + aA1, sB = aB0 + aB1;
            float bv = bias[n * 16 + l15];
            #pragma unroll
            for (int r2 = 0; r2 < 4; ++r2) {
                int off = ks_off(R + quad * 4 + r2, n * 16 + l15);
                float vA = sA[r2] + bv, vB = sB[r2] + bv;
                if (RELU) { vA = fmaxf(vA, 0.f); vB = fmaxf(vB, 0.f); }
                *(bf16_t*)(u_lds + off)         = (bf16_t)vA;
                *(bf16_t*)(u_lds + 32768 + off) = (bf16_t)vB;
            }
        }
    }
}

// ---------------- R13 main kernel (ws path) ----------------
__global__ __launch_bounds__(256, 2)
void policy_fused(const float* __restrict__ x,
                  const bf16_t* __restrict__ wfA,
                  const bf16_t* __restrict__ wfM,
                  const float* __restrict__ flt,   // c2|v|w4p|pb|s0
                  const float* __restrict__ b1,
                  const int*   __restrict__ gidx,
                  float* __restrict__ out,
                  int nbat) {
    // u_lds: out (64x256 bf16, swizzled) x2 batches; later aliased as fullbuf.
    // uq: union { L1 weight-stage ring (2x4KB=8KB) | qscr (10,240B) }.
    __shared__ __align__(16) unsigned char u_lds[2 * 32768];
    __shared__ __align__(16) unsigned char uq[10240];
    __shared__ float promoLDS[2][4][8];
    __shared__ float patchLDS[2][8][8];

    const int tid  = threadIdx.x;
    const int lane = tid & 63;
    const int wv   = tid >> 6;
    const int quad = lane >> 4;
    const int l15  = lane & 15;
    const int R    = wv * 16;

    const int bat0 = blockIdx.x * 2;
    const bool has1 = (bat0 + 1) < nbat;
    const int bat1 = has1 ? bat0 + 1 : bat0;

    // ---- x A-fragments ----
    bf16x8 xaA[8], xaB[8];
    {
        const float* xr0 = x + ((size_t)bat0 * 64 + R + l15) * 256;
        const float* xr1 = x + ((size_t)bat1 * 64 + R + l15) * 256;
        #pragma unroll
        for (int t = 0; t < 8; ++t) {
            xaA[t] = cvt8(xr0 + t * 32 + quad * 8);
            xaB[t] = cvt8(xr1 + t * 32 + quad * 8);
        }
    }

    // ---------------- layer 1 (staged weights): out = relu(x@w1.T+b1) -------
    layer_staged<true>(xaA, xaB, wfA, b1, u_lds, uq, wv, lane, quad, l15, R);

    // ---- oa readback (own rows; same-wave DS ordering) ----
    bf16x8 oaA[8], oaB[8];
    #pragma unroll
    for (int t = 0; t < 8; ++t) {
        int off = ks_off(R + l15, t * 32 + quad * 8);
        oaA[t] = *(const bf16x8*)(u_lds + off);
        oaB[t] = *(const bf16x8*)(u_lds + 32768 + off);
    }

    // ---- qb[i] = out[i,:]·v + s0 (per-lane row = R + l15) ----
    float qbA = flt[1540], qbB = qbA;
    {
        const float* vvec = flt + 256;
        #pragma unroll
        for (int t = 0; t < 8; ++t) {
            f32x4 va = *(const f32x4*)(vvec + t * 32 + quad * 8);
            f32x4 vb = *(const f32x4*)(vvec + t * 32 + quad * 8 + 4);
            qbA += (float)oaA[t][0]*va[0] + (float)oaA[t][1]*va[1]
                 + (float)oaA[t][2]*va[2] + (float)oaA[t][3]*va[3]
                 + (float)oaA[t][4]*vb[0] + (float)oaA[t][5]*vb[1]
                 + (float)oaA[t][6]*vb[2] + (float)oaA[t][7]*vb[3];
            qbB += (float)oaB[t][0]*va[0] + (float)oaB[t][1]*va[1]
                 + (float)oaB[t][2]*va[2] + (float)oaB[t][3]*va[3]
                 + (float)oaB[t][4]*vb[0] + (float)oaB[t][5]*vb[1]
                 + (float)oaB[t][6]*vb[2] + (float)oaB[t][7]*vb[3];
        }
        qbA += __shfl_xor(qbA, 16);  qbA += __shfl_xor(qbA, 32);
        qbB += __shfl_xor(qbB, 16);  qbB += __shfl_xor(qbB, 32);
        // qbA/qbB now functions of l15 only: qb for row R+l15
    }

    // first fused wA prefetch hoisted above the barrier (global-only dep)
    bf16x8 wA[4], wB[4];
    #pragma unroll
    for (int t = 0; t < 4; ++t)
        wA[t] = wfrag<true>(wfM, nullptr, 0, t, lane);

    __syncthreads();   // #1: out complete across waves; L1 staging reads done

    // ------- fused q2 (= out@M + c2) + logits (= q2@out^T), R9 form ---------
    f32x4 laA[4], laB[4];
    #pragma unroll
    for (int n = 0; n < 4; ++n) {
        laA[n] = (f32x4){0.f,0.f,0.f,0.f};
        laB[n] = (f32x4){0.f,0.f,0.f,0.f};
    }
    {
        bf16_t* qsA = (bf16_t*)uq + (wv * 2 + 0) * 640;
        bf16_t* qsB = (bf16_t*)uq + (wv * 2 + 1) * 640;

        #pragma unroll
        for (int t8 = 0; t8 < 8; ++t8) {
            const int n0 = 2 * t8, n1 = n0 + 1;

            // ---- q2 tile n0 ----
            #pragma unroll
            for (int t = 0; t < 4; ++t)
                wB[t] = wfrag<true>(wfM, nullptr, n0, 4 + t, lane);
            {
                f32x4 cA0 = {0.f,0.f,0.f,0.f}, cA1 = {0.f,0.f,0.f,0.f};
                f32x4 cB0 = {0.f,0.f,0.f,0.f}, cB1 = {0.f,0.f,0.f,0.f};
                cA0 = MFMA(oaA[0], wA[0], cA0);  cB0 = MFMA(oaB[0], wA[0], cB0);
                cA1 = MFMA(oaA[1], wA[1], cA1);  cB1 = MFMA(oaB[1], wA[1], cB1);
                cA0 = MFMA(oaA[2], wA[2], cA0);  cB0 = MFMA(oaB[2], wA[2], cB0);
                cA1 = MFMA(oaA[3], wA[3], cA1);  cB1 = MFMA(oaB[3], wA[3], cB1);
                #pragma unroll
                for (int t = 0; t < 4; ++t)
                    wA[t] = wfrag<true>(wfM, nullptr, n1, t, lane);
                cA0 = MFMA(oaA[4], wB[0], cA0);  cB0 = MFMA(oaB[4], wB[0], cB0);
                cA1 = MFMA(oaA[5], wB[1], cA1);  cB1 = MFMA(oaB[5], wB[1], cB1);
                cA0 = MFMA(oaA[6], wB[2], cA0);  cB0 = MFMA(oaB[6], wB[2], cB0);
                cA1 = MFMA(oaA[7], wB[3], cA1);  cB1 = MFMA(oaB[7], wB[3], cB1);
                f32x4 sA = cA0 + cA1, sB = cB0 + cB1;
                float bv = flt[n0 * 16 + l15];           // c2
                #pragma unroll
                for (int r2 = 0; r2 < 4; ++r2) {
                    int qo = (quad * 4 + r2) * 40 + l15;
                    qsA[qo] = (bf16_t)(sA[r2] + bv);
                    qsB[qo] = (bf16_t)(sB[r2] + bv);
                }
            }

            // ---- q2 tile n1 ----
            #pragma unroll
            for (int t = 0; t < 4; ++t)
                wB[t] = wfrag<true>(wfM, nullptr, n1, 4 + t, lane);
            {
                f32x4 cA0 = {0.f,0.f,0.f,0.f}, cA1 = {0.f,0.f,0.f,0.f};
                f32x4 cB0 = {0.f,0.f,0.f,0.f}, cB1 = {0.f,0.f,0.f,0.f};
                cA0 = MFMA(oaA[0], wA[0], cA0);  cB0 = MFMA(oaB[0], wA[0], cB0);
                cA1 = MFMA(oaA[1], wA[1], cA1);  cB1 = MFMA(oaB[1], wA[1], cB1);
                cA0 = MFMA(oaA[2], wA[2], cA0);  cB0 = MFMA(oaB[2], wA[2], cB0);
                cA1 = MFMA(oaA[3], wA[3], cA1);  cB1 = MFMA(oaB[3], wA[3], cB1);
                if (t8 < 7) {
                    #pragma unroll
                    for (int t = 0; t < 4; ++t)
                        wA[t] = wfrag<true>(wfM, nullptr, n0 + 2, t, lane);
                }
                cA0 = MFMA(oaA[4], wB[0], cA0);  cB0 = MFMA(oaB[4], wB[0], cB0);
                cA1 = MFMA(oaA[5], wB[1], cA1);  cB1 = MFMA(oaB[5], wB[1], cB1);
                cA0 = MFMA(oaA[6], wB[2], cA0);  cB0 = MFMA(oaB[6], wB[2], cB0);
                cA1 = MFMA(oaA[7], wB[3], cA1);  cB1 = MFMA(oaB[7], wB[3], cB1);
                f32x4 sA = cA0 + cA1, sB = cB0 + cB1;
                float bv = flt[n1 * 16 + l15];           // c2
                #pragma unroll
                for (int r2 = 0; r2 < 4; ++r2) {
                    int qo = (quad * 4 + r2) * 40 + 16 + l15;
                    qsA[qo] = (bf16_t)(sA[r2] + bv);
                    qsB[qo] = (bf16_t)(sB[r2] + bv);
                }
            }

            // ---- read q2 slice (A-operand order), 8 logits MFMAs vs out ----
            bf16x8 qaA = *(const bf16x8*)(qsA + l15 * 40 + quad * 8);
            bf16x8 qaB = *(const bf16x8*)(qsB + l15 * 40 + quad * 8);
            #pragma unroll
            for (int np = 0; np < 4; ++np) {
                int ko = ks_off(np * 16 + l15, t8 * 32 + quad * 8);
                bf16x8 kA = *(const bf16x8*)(u_lds + ko);
                bf16x8 kB = *(const bf16x8*)(u_lds + 32768 + ko);
                laA[np] = MFMA(qaA, kA, laA[np]);
                laB[np] = MFMA(qaB, kB, laB[np]);
            }
        }
    }

    // ---- per-row qb broadcast (row = quad*4+r2 of this wave) ----
    float qbra[4], qbrb[4];
    #pragma unroll
    for (int r2 = 0; r2 < 4; ++r2) {
        qbra[r2] = __shfl(qbA, quad * 4 + r2);
        qbrb[r2] = __shfl(qbB, quad * 4 + r2);
    }

    // ---------------- promo: offs[p][s] = w4p[p]·out[56+s] + pb[p] ----------
    {
        int s = lane >> 3, seg = lane & 7;     // wave wv handles p = wv
        const float* wrow = flt + 512 + wv * 256;
        #pragma unroll
        for (int b = 0; b < 2; ++b) {
            const unsigned char* kb = u_lds + b * 32768;
            float p = 0.f;
            #pragma unroll
            for (int m = 0; m < 4; ++m) {
                bf16x8 kv = *(const bf16x8*)(kb + ks_off(56 + s, seg * 32 + m * 8));
                f32x4 wa = *(const f32x4*)(wrow + seg * 32 + m * 8);
                f32x4 wb = *(const f32x4*)(wrow + seg * 32 + m * 8 + 4);
                p += (float)kv[0] * wa[0] + (float)kv[1] * wa[1]
                   + (float)kv[2] * wa[2] + (float)kv[3] * wa[3]
                   + (float)kv[4] * wb[0] + (float)kv[5] * wb[1]
                   + (float)kv[6] * wb[2] + (float)kv[7] * wb[3];
            }
            p += __shfl_down(p, 4);
            p += __shfl_down(p, 2);
            p += __shfl_down(p, 1);
            if (seg == 0) promoLDS[b][wv][s] = p + flt[1536 + wv];   // + pb[p]
        }
    }

    // wave 3 stages the logits[48:56, 56:64] patch (incl. qb!)
    if (wv == 3 && quad < 2 && l15 >= 8) {
        #pragma unroll
        for (int r2 = 0; r2 < 4; ++r2) {
            patchLDS[0][quad * 4 + r2][l15 - 8] = (laA[3][r2] + qbra[r2]) * PSCALE;
            patchLDS[1][quad * 4 + r2][l15 - 8] = (laB[3][r2] + qbrb[r2]) * PSCALE;
        }
    }

    __syncthreads();   // #2: everyone done READING out; promoLDS/patch ready

    // ---------------- fullbuf (aliased over out regions) --------------------
    float* fb0 = (float*)u_lds;
    float* fb1 = (float*)(u_lds + 32768);
    #pragma unroll
    for (int n = 0; n < 4; ++n) {
        #pragma unroll
        for (int r2 = 0; r2 < 4; ++r2) {
            int idx = (R + quad * 4 + r2) * 64 + n * 16 + l15;
            fb0[idx] = (laA[n][r2] + qbra[r2]) * PSCALE;
            fb1[idx] = (laB[n][r2] + qbrb[r2]) * PSCALE;
        }
    }

    // promo rows 64..66
    if (tid < 192) {
        int u = tid >> 6, vv2 = tid & 63;
        int mm = u * 64 + vv2;
        int r_ = mm / 24, c_ = mm - r_ * 24;
        int c3 = c_ / 3, cp = c_ - c3 * 3;
        fb0[(64 + u) * 64 + vv2] =
            promoLDS[0][cp][c3] + promoLDS[0][3][c3] + patchLDS[0][r_][c3];
        fb1[(64 + u) * 64 + vv2] =
            promoLDS[1][cp][c3] + promoLDS[1][3][c3] + patchLDS[1][r_][c3];
    }

    __syncthreads();   // #3: fullbufs ready

    // ---------------- gather ------------------------------------------------
    {
        float* orow0 = out + (size_t)bat0 * NPOL;
        float* orow1 = out + (size_t)(bat0 + 1) * NPOL;
        int   idxv[8];
        float v0[8], v1[8];
        #pragma unroll
        for (int i = 0; i < 8; ++i) {
            int g = tid + i * 256;
            idxv[i] = (g < NPOL) ? gidx[g] : 0;
        }
        #pragma unroll
        for (int i = 0; i < 8; ++i) {
            v0[i] = fb0[idxv[i]];
            v1[i] = fb1[idxv[i]];
        }
        #pragma unroll
        for (int i = 0; i < 8; ++i) {
            int g = tid + i * 256;
            if (g < NPOL) {
                orow0[g] = v0[i];
                if (has1) orow1[g] = v1[i];
            }
        }
    }
}

// ---------------- fallback kernel (no-workspace path, R9 structure) ---------
__device__ __forceinline__ void mfma16f(const bf16x8* inA, const bf16x8* inB,
                                        const bf16x8* w, f32x4& s0, f32x4& s1) {
    f32x4 a00 = {0.f,0.f,0.f,0.f}, a01 = {0.f,0.f,0.f,0.f};
    f32x4 a10 = {0.f,0.f,0.f,0.f}, a11 = {0.f,0.f,0.f,0.f};
    #pragma unroll
    for (int t = 0; t < 8; t += 2) {
        a00 = MFMA(inA[t],     w[t],     a00);
        a10 = MFMA(inB[t],     w[t],     a10);
        a01 = MFMA(inA[t + 1], w[t + 1], a01);
        a11 = MFMA(inB[t + 1], w[t + 1], a11);
    }
    s0 = a00 + a01;
    s1 = a10 + a11;
}

template <bool RELU>
__device__ __forceinline__ void layer_raw(const bf16x8* inA, const bf16x8* inB,
                                          const float* __restrict__ wraw,
                                          const float* __restrict__ bias,
                                          unsigned char* __restrict__ u_lds,
                                          int lane, int quad, int l15, int R) {
    bf16x8 wA[4], wB[4];
    #pragma unroll
    for (int t = 0; t < 4; ++t)
        wA[t] = wfrag<false>(nullptr, wraw, 0, t, lane);
    #pragma unroll
    for (int n = 0; n < 16; ++n) {
        #pragma unroll
        for (int t = 0; t < 4; ++t)
            wB[t] = wfrag<false>(nullptr, wraw, n, 4 + t, lane);
        f32x4 aA0 = {0.f,0.f,0.f,0.f}, aA1 = {0.f,0.f,0.f,0.f};
        f32x4 aB0 = {0.f,0.f,0.f,0.f}, aB1 = {0.f,0.f,0.f,0.f};
        aA0 = MFMA(inA[0], wA[0], aA0);  aB0 = MFMA(inB[0], wA[0], aB0);
        aA1 = MFMA(inA[1], wA[1], aA1);  aB1 = MFMA(inB[1], wA[1], aB1);
        aA0 = MFMA(inA[2], wA[2], aA0);  aB0 = MFMA(inB[2], wA[2], aB0);
        aA1 = MFMA(inA[3], wA[3], aA1);  aB1 = MFMA(inB[3], wA[3], aB1);
        if (n < 15) {
            #pragma unroll
            for (int t = 0; t < 4; ++t)
                wA[t] = wfrag<false>(nullptr, wraw, n + 1, t, lane);
        }
        aA0 = MFMA(inA[4], wB[0], aA0);  aB0 = MFMA(inB[4], wB[0], aB0);
        aA1 = MFMA(inA[5], wB[1], aA1);  aB1 = MFMA(inB[5], wB[1], aB1);
        aA0 = MFMA(inA[6], wB[2], aA0);  aB0 = MFMA(inB[6], wB[2], aB0);
        aA1 = MFMA(inA[7], wB[3], aA1);  aB1 = MFMA(inB[7], wB[3], aB1);
        f32x4 sA = aA0 + aA1, sB = aB0 + aB1;
        float bv = bias[n * 16 + l15];
        #pragma unroll
        for (int r2 = 0; r2 < 4; ++r2) {
            int off = ks_off(R + quad * 4 + r2, n * 16 + l15);
            float vA = sA[r2] + bv, vB = sB[r2] + bv;
            if (RELU) { vA = fmaxf(vA, 0.f); vB = fmaxf(vB, 0.f); }
            *(bf16_t*)(u_lds + off)         = (bf16_t)vA;
            *(bf16_t*)(u_lds + 32768 + off) = (bf16_t)vB;
        }
    }
}

__global__ __launch_bounds__(256, 2)
void policy_main(const float* __restrict__ x,
                 const float* __restrict__ w1,
                 const float* __restrict__ w2,
                 const float* __restrict__ w3,
                 const float* __restrict__ b1,
                 const float* __restrict__ b2,
                 const float* __restrict__ b3,
                 const float* __restrict__ w4,
                 const int*   __restrict__ gidx,
                 float* __restrict__ out,
                 int nbat) {
    __shared__ __align__(16) unsigned char u_lds[2 * 32768];
    __shared__ __align__(16) bf16_t qscr[4][2][16 * 40];
    __shared__ float promoLDS[2][4][8];
    __shared__ float patchLDS[2][8][8];

    const int tid  = threadIdx.x;
    const int lane = tid & 63;
    const int wv   = tid >> 6;
    const int quad = lane >> 4;
    const int l15  = lane & 15;
    const int R    = wv * 16;

    const int bat0 = blockIdx.x * 2;
    const bool has1 = (bat0 + 1) < nbat;
    const int bat1 = has1 ? bat0 + 1 : bat0;

    bf16x8 xaA[8], xaB[8];
    {
        const float* xr0 = x + ((size_t)bat0 * 64 + R + l15) * 256;
        const float* xr1 = x + ((size_t)bat1 * 64 + R + l15) * 256;
        #pragma unroll
        for (int t = 0; t < 8; ++t) {
            xaA[t] = cvt8(xr0 + t * 32 + quad * 8);
            xaB[t] = cvt8(xr1 + t * 32 + quad * 8);
        }
    }

    layer_raw<true>(xaA, xaB, w1, b1, u_lds, lane, quad, l15, R);
    bf16x8 oaA[8], oaB[8];
    #pragma unroll
    for (int t = 0; t < 8; ++t) {
        int off = ks_off(R + l15, t * 32 + quad * 8);
        oaA[t] = *(const bf16x8*)(u_lds + off);
        oaB[t] = *(const bf16x8*)(u_lds + 32768 + off);
    }

    layer_raw<false>(oaA, oaB, w3, b3, u_lds, lane, quad, l15, R);

    __syncthreads();

    f32x4 laA[4], laB[4];
    #pragma unroll
    for (int n = 0; n < 4; ++n) {
        laA[n] = (f32x4){0.f,0.f,0.f,0.f};
        laB[n] = (f32x4){0.f,0.f,0.f,0.f};
    }
    {
        bf16_t* qsA = &qscr[wv][0][0];
        bf16_t* qsB = &qscr[wv][1][0];
        bf16x8 wA[4], wB[4];
        #pragma unroll
        for (int t = 0; t < 4; ++t)
            wA[t] = wfrag<false>(nullptr, w2, 0, t, lane);

        #pragma unroll
        for (int t8 = 0; t8 < 8; ++t8) {
            const int n0 = 2 * t8, n1 = n0 + 1;
            #pragma unroll
            for (int t = 0; t < 4; ++t)
                wB[t] = wfrag<false>(nullptr, w2, n0, 4 + t, lane);
            {
                f32x4 sA, sB;
                bf16x8 wfull[8] = {wA[0], wA[1], wA[2], wA[3],
                                   wB[0], wB[1], wB[2], wB[3]};
                mfma16f(oaA, oaB, wfull, sA, sB);
                float bv = b2[n0 * 16 + l15];
                #pragma unroll
                for (int r2 = 0; r2 < 4; ++r2) {
                    int qo = (quad * 4 + r2) * 40 + l15;
                    qsA[qo] = (bf16_t)(sA[r2] + bv);
                    qsB[qo] = (bf16_t)(sB[r2] + bv);
                }
            }
            #pragma unroll
            for (int t = 0; t < 4; ++t)
                wA[t] = wfrag<false>(nullptr, w2, n1, t, lane);
            #pragma unroll
            for (int t = 0; t < 4; ++t)
                wB[t] = wfrag<false>(nullptr, w2, n1, 4 + t, lane);
            {
                f32x4 sA, sB;
                bf16x8 wfull[8] = {wA[0], wA[1], wA[2], wA[3],
                                   wB[0], wB[1], wB[2], wB[3]};
                mfma16f(oaA, oaB, wfull, sA, sB);
                float bv = b2[n1 * 16 + l15];
                #pragma unroll
                for (int r2 = 0; r2 < 4; ++r2) {
                    int qo = (quad * 4 + r2) * 40 + 16 + l15;
                    qsA[qo] = (bf16_t)(sA[r2] + bv);
                    qsB[qo] = (bf16_t)(sB[r2] + bv);
                }
            }
            if (t8 < 7) {
                #pragma unroll
                for (int t = 0; t < 4; ++t)
                    wA[t] = wfrag<false>(nullptr, w2, n0 + 2, t, lane);
            }
            bf16x8 qaA = *(const bf16x8*)(qsA + l15 * 40 + quad * 8);
            bf16x8 qaB = *(const bf16x8*)(qsB + l15 * 40 + quad * 8);
            #pragma unroll
            for (int np = 0; np < 4; ++np) {
                int ko = ks_off(np * 16 + l15, t8 * 32 + quad * 8);
                bf16x8 kA = *(const bf16x8*)(u_lds + ko);
                bf16x8 kB = *(const bf16x8*)(u_lds + 32768 + ko);
                laA[np] = MFMA(qaA, kA, laA[np]);
                laB[np] = MFMA(qaB, kB, laB[np]);
            }
        }
    }

    {
        int s = lane >> 3, seg = lane & 7;
        const float* wrow = w4 + wv * 256;
        #pragma unroll
        for (int b = 0; b < 2; ++b) {
            const unsigned char* kb = u_lds + b * 32768;
            float p = 0.f;
            #pragma unroll
            for (int m = 0; m < 4; ++m) {
                bf16x8 kv = *(const bf16x8*)(kb + ks_off(56 + s, seg * 32 + m * 8));
                f32x4 wa = *(const f32x4*)(wrow + seg * 32 + m * 8);
                f32x4 wb = *(const f32x4*)(wrow + seg * 32 + m * 8 + 4);
                p += (float)kv[0] * wa[0] + (float)kv[1] * wa[1]
                   + (float)kv[2] * wa[2] + (float)kv[3] * wa[3]
                   + (float)kv[4] * wb[0] + (float)kv[5] * wb[1]
                   + (float)kv[6] * wb[2] + (float)kv[7] * wb[3];
            }
            p += __shfl_down(p, 4);
            p += __shfl_down(p, 2);
            p += __shfl_down(p, 1);
            if (seg == 0) promoLDS[b][wv][s] = p;
        }
    }

    if (wv == 3 && quad < 2 && l15 >= 8) {
        #pragma unroll
        for (int r2 = 0; r2 < 4; ++r2) {
            patchLDS[0][quad * 4 + r2][l15 - 8] = laA[3][r2] * PSCALE;
            patchLDS[1][quad * 4 + r2][l15 - 8] = laB[3][r2] * PSCALE;
        }
    }

    __syncthreads();

    float* fb0 = (float*)u_lds;
    float* fb1 = (float*)(u_lds + 32768);
    #pragma unroll
    for (int n = 0; n < 4; ++n) {
        #pragma unroll
        for (int r2 = 0; r2 < 4; ++r2) {
            int idx = (R + quad * 4 + r2) * 64 + n * 16 + l15;
            fb0[idx] = laA[n][r2] * PSCALE;
            fb1[idx] = laB[n][r2] * PSCALE;
        }
    }

    if (tid < 192) {
        int u = tid >> 6, vv2 = tid & 63;
        int mm = u * 64 + vv2;
        int r_ = mm / 24, c_ = mm - r_ * 24;
        int c3 = c_ / 3, cp = c_ - c3 * 3;
        fb0[(64 + u) * 64 + vv2] =
            promoLDS[0][cp][c3] + promoLDS[0][3][c3] + patchLDS[0][r_][c3];
        fb1[(64 + u) * 64 + vv2] =
            promoLDS[1][cp][c3] + promoLDS[1][3][c3] + patchLDS[1][r_][c3];
    }

    __syncthreads();

    {
        float* orow0 = out + (size_t)bat0 * NPOL;
        float* orow1 = out + (size_t)(bat0 + 1) * NPOL;
        int   idxv[8];
        float v0[8], v1[8];
        #pragma unroll
        for (int i = 0; i < 8; ++i) {
            int g = tid + i * 256;
            idxv[i] = (g < NPOL) ? gidx[g] : 0;
        }
        #pragma unroll
        for (int i = 0; i < 8; ++i) {
            v0[i] = fb0[idxv[i]];
            v1[i] = fb1[idxv[i]];
        }
        #pragma unroll
        for (int i = 0; i < 8; ++i) {
            int g = tid + i * 256;
            if (g < NPOL) {
                orow0[g] = v0[i];
                if (has1) orow1[g] = v1[i];
            }
        }
    }
}

extern "C" void kernel_launch(void* const* d_in, const int* in_sizes, int n_in,
                              void* d_out, int out_size, void* d_ws, size_t ws_size,
                              hipStream_t stream) {
    const float* x    = (const float*)d_in[0];
    const float* w1   = (const float*)d_in[1];
    const float* b1   = (const float*)d_in[2];
    const float* w2   = (const float*)d_in[3];
    const float* b2   = (const float*)d_in[4];
    const float* w3   = (const float*)d_in[5];
    const float* b3   = (const float*)d_in[6];
    const float* w4   = (const float*)d_in[7];
    const int*   gidx = (const int*)d_in[8];
    float* out = (float*)d_out;

    int nbat = in_sizes[0] / (64 * 256);        // 4096
    int nblk = (nbat + 1) / 2;
    const size_t ws_needed = 262144 + 8192;     // wfA+wfM (256K) + float region

    if (ws_size >= ws_needed) {
        bf16_t* wfA = (bf16_t*)d_ws;
        bf16_t* wfM = wfA + 65536;
        float*  flt = (float*)((char*)d_ws + 262144);
        prep_w1  <<<256, 256, 0, stream>>>(w1, wfA);
        prep_mat <<<256, 256, 0, stream>>>(w2, w3, wfM);
        prep_vecs<<<1,   256, 0, stream>>>(w2, w3, b2, b3, w4, flt);
        policy_fused<<<nblk, 256, 0, stream>>>(
            x, wfA, wfM, flt, b1, gidx, out, nbat);
    } else {
        policy_main<<<nblk, 256, 0, stream>>>(
            x, w1, w2, w3, b1, b2, b3, w4, gidx, out, nbat);
    }
}

// Round 12
// 503.989 us; speedup vs baseline: 1.0637x; 1.0486x over previous
//
#include <hip/hip_runtime.h>

// PolicyHead fused kernel, R14 = R9 (best, 185us) + micro-tunes.
// R10-R13 post-mortems mapped the wall: stall-points x loads-in-flight is
// pinned by the 128-arch-reg cap, and every structural escape (1-wave deep
// prefetch R10, LDS A-ops R11, 8-wave split R12, staged weights R13) loses
// more to spills/lockstep than it gains. R9's shape is the optimum:
// 256 thr / 2 batches / 2 independent blocks/CU / algebraic k-elimination.
// R14 micro-tunes (structure-preserving):
//  - s_setprio(1) around MFMA clusters: 2 independent blocks/CU drift in
//    phase -> MFMA-ready waves preempt load-issuing waves (attn-style win).
//  - first fused wA prefetch hoisted above barrier #1 (latency drains with
//    the barrier).
//  - qb parked in 512B LDS right after L1 (frees the ~6 live regs behind
//    R9's 4MB spill tail).

typedef __bf16 bf16_t;
typedef __bf16 bf16x8 __attribute__((ext_vector_type(8)));
typedef float  f32x4  __attribute__((ext_vector_type(4)));

#define PSCALE 0.0625f
#define NPOL   1858
#define MFMA(a,b,c) __builtin_amdgcn_mfma_f32_16x16x32_bf16(a, b, c, 0, 0, 0)

// ---------------- prep kernels (ws path) ----------------
// ws layout: [0,128K) wfA = w1 frags bf16; [128K,256K) wfM = M frags bf16;
// [256K..) float region: c2[256] | v[256] | w4p[4][256] | pb[4] | s0.

__global__ void prep_w1(const float* __restrict__ w1, bf16_t* __restrict__ wfA) {
    int i = blockIdx.x * 256 + threadIdx.x;      // 0..65535
    int j = i & 7, lane = (i >> 3) & 63, t = (i >> 9) & 7, n = (i >> 12) & 15;
    int row = n * 16 + (lane & 15);              // output-col (w1 row)
    int col = t * 32 + (lane >> 4) * 8 + j;      // k index
    wfA[i] = (bf16_t)w1[row * 256 + col];
}

// M[m1][m2] = sum_h w2[h][m1]*w3[h][m2], written directly in B-frag layout
// for q2 = out @ M (frag elem = M[t*32+quad*8+j][n*16+l15]).
__global__ void prep_mat(const float* __restrict__ w2,
                         const float* __restrict__ w3,
                         bf16_t* __restrict__ wfM) {
    int m1 = blockIdx.x, m2 = threadIdx.x;
    float acc = 0.f;
    #pragma unroll 8
    for (int h = 0; h < 256; ++h)
        acc += w2[h * 256 + m1] * w3[h * 256 + m2];
    int t = m1 >> 5, quad = (m1 >> 3) & 3, j = m1 & 7;
    int n = m2 >> 4, l15 = m2 & 15;
    wfM[(((n * 8 + t) * 64) + (quad * 16 + l15)) * 8 + j] = (bf16_t)acc;
}

__global__ void prep_vecs(const float* __restrict__ w2,
                          const float* __restrict__ w3,
                          const float* __restrict__ b2,
                          const float* __restrict__ b3,
                          const float* __restrict__ w4,
                          float* __restrict__ flt) {
    int m = threadIdx.x;
    float c2 = 0.f, vv = 0.f, p0 = 0.f, p1 = 0.f, p2 = 0.f, p3 = 0.f;
    for (int h = 0; h < 256; ++h) {
        float w3h = w3[h * 256 + m];
        c2 += b2[h] * w3h;
        p0 += w4[h] * w3h;
        p1 += w4[256 + h] * w3h;
        p2 += w4[512 + h] * w3h;
        p3 += w4[768 + h] * w3h;
        vv += w2[h * 256 + m] * b3[h];
    }
    flt[m]        = c2;                          // c2[m]
    flt[256 + m]  = vv;                          // v[m]
    flt[512 + m]  = p0;                          // w4p[0][m]
    flt[768 + m]  = p1;
    flt[1024 + m] = p2;
    flt[1280 + m] = p3;
    if (m < 4) {
        float pb = 0.f;
        for (int h = 0; h < 256; ++h) pb += w4[m * 256 + h] * b3[h];
        flt[1536 + m] = pb;                      // pb[p]
    }
    if (m == 0) {
        float s = 0.f;
        for (int h = 0; h < 256; ++h) s += b2[h] * b3[h];
        flt[1540] = s;                           // s0
    }
}

// ---------------- shared device helpers ----------------

template <bool USE_WS>
__device__ __forceinline__ bf16x8 wfrag(const bf16_t* __restrict__ wl,
                                        const float* __restrict__ w,
                                        int n, int t, int lane) {
    if constexpr (USE_WS) {
        return *(const bf16x8*)(wl + (((n * 8 + t) * 64 + lane) << 3));
    } else {
        int l15 = lane & 15, quad = lane >> 4;
        const float* p = w + (n * 16 + l15) * 256 + t * 32 + quad * 8;
        f32x4 lo = *(const f32x4*)p;
        f32x4 hi = *(const f32x4*)(p + 4);
        bf16x8 v;
        v[0] = (bf16_t)lo[0]; v[1] = (bf16_t)lo[1];
        v[2] = (bf16_t)lo[2]; v[3] = (bf16_t)lo[3];
        v[4] = (bf16_t)hi[0]; v[5] = (bf16_t)hi[1];
        v[6] = (bf16_t)hi[2]; v[7] = (bf16_t)hi[3];
        return v;
    }
}

// Swizzled byte offset into a 64x256 bf16 buffer (32768 B).
__device__ __forceinline__ int ks_off(int row, int col) {
    return ((row << 9) + (col << 1)) ^ ((row & 7) << 4);
}

__device__ __forceinline__ bf16x8 cvt8(const float* __restrict__ p) {
    f32x4 lo = *(const f32x4*)p;
    f32x4 hi = *(const f32x4*)(p + 4);
    bf16x8 v;
    v[0] = (bf16_t)lo[0]; v[1] = (bf16_t)lo[1];
    v[2] = (bf16_t)lo[2]; v[3] = (bf16_t)lo[3];
    v[4] = (bf16_t)hi[0]; v[5] = (bf16_t)hi[1];
    v[6] = (bf16_t)hi[2]; v[7] = (bf16_t)hi[3];
    return v;
}

// Full 256->256 layer, both batches, half-tile (4-frag) weight prefetch.
// setprio(1) while the MFMA cluster runs; (0) while issuing loads/stores.
template <bool USE_WS, bool RELU>
__device__ __forceinline__ void layer2b(const bf16x8* inA, const bf16x8* inB,
                                        const bf16_t* __restrict__ wl,
                                        const float* __restrict__ wraw,
                                        const float* __restrict__ bias,
                                        unsigned char* __restrict__ u_lds,
                                        int lane, int quad, int l15, int R) {
    bf16x8 wA[4], wB[4];
    #pragma unroll
    for (int t = 0; t < 4; ++t)
        wA[t] = wfrag<USE_WS>(wl, wraw, 0, t, lane);

    #pragma unroll
    for (int n = 0; n < 16; ++n) {
        #pragma unroll
        for (int t = 0; t < 4; ++t)
            wB[t] = wfrag<USE_WS>(wl, wraw, n, 4 + t, lane);

        f32x4 aA0 = {0.f,0.f,0.f,0.f}, aA1 = {0.f,0.f,0.f,0.f};
        f32x4 aB0 = {0.f,0.f,0.f,0.f}, aB1 = {0.f,0.f,0.f,0.f};
        __builtin_amdgcn_s_setprio(1);
        aA0 = MFMA(inA[0], wA[0], aA0);  aB0 = MFMA(inB[0], wA[0], aB0);
        aA1 = MFMA(inA[1], wA[1], aA1);  aB1 = MFMA(inB[1], wA[1], aB1);
        aA0 = MFMA(inA[2], wA[2], aA0);  aB0 = MFMA(inB[2], wA[2], aB0);
        aA1 = MFMA(inA[3], wA[3], aA1);  aB1 = MFMA(inB[3], wA[3], aB1);
        __builtin_amdgcn_s_setprio(0);

        if (n < 15) {
            #pragma unroll
            for (int t = 0; t < 4; ++t)
                wA[t] = wfrag<USE_WS>(wl, wraw, n + 1, t, lane);
        }

        __builtin_amdgcn_s_setprio(1);
        aA0 = MFMA(inA[4], wB[0], aA0);  aB0 = MFMA(inB[4], wB[0], aB0);
        aA1 = MFMA(inA[5], wB[1], aA1);  aB1 = MFMA(inB[5], wB[1], aB1);
        aA0 = MFMA(inA[6], wB[2], aA0);  aB0 = MFMA(inB[6], wB[2], aB0);
        aA1 = MFMA(inA[7], wB[3], aA1);  aB1 = MFMA(inB[7], wB[3], aB1);
        __builtin_amdgcn_s_setprio(0);

        f32x4 sA = aA0 + aA1, sB = aB0 + aB1;
        float bv = bias[n * 16 + l15];
        #pragma unroll
        for (int r2 = 0; r2 < 4; ++r2) {
            int off = ks_off(R + quad * 4 + r2, n * 16 + l15);
            float vA = sA[r2] + bv, vB = sB[r2] + bv;
            if (RELU) { vA = fmaxf(vA, 0.f); vB = fmaxf(vB, 0.f); }
            *(bf16_t*)(u_lds + off)         = (bf16_t)vA;
            *(bf16_t*)(u_lds + 32768 + off) = (bf16_t)vB;
        }
    }
}

// ---------------- R14 main kernel (ws path) ----------------
__global__ __launch_bounds__(256, 2)
void policy_fused(const float* __restrict__ x,
                  const bf16_t* __restrict__ wfA,
                  const bf16_t* __restrict__ wfM,
                  const float* __restrict__ flt,   // c2|v|w4p|pb|s0
                  const float* __restrict__ b1,
                  const int*   __restrict__ gidx,
                  float* __restrict__ out,
                  int nbat) {
    // Two 32768 B unions: phase A = out (64x256 bf16, XOR-swizzled) per batch;
    //                     phase B = fullbuf (67x64 f32) per batch.
    __shared__ __align__(16) unsigned char u_lds[2 * 32768];
    __shared__ __align__(16) bf16_t qscr[4][2][16 * 40];  // per-wave q2 transpose
    __shared__ float promoLDS[2][4][8];
    __shared__ float patchLDS[2][8][8];
    __shared__ float qbLDS[2][64];

    const int tid  = threadIdx.x;
    const int lane = tid & 63;
    const int wv   = tid >> 6;
    const int quad = lane >> 4;
    const int l15  = lane & 15;
    const int R    = wv * 16;

    const int bat0 = blockIdx.x * 2;
    const bool has1 = (bat0 + 1) < nbat;
    const int bat1 = has1 ? bat0 + 1 : bat0;

    // ---- x A-fragments ----
    bf16x8 xaA[8], xaB[8];
    {
        const float* xr0 = x + ((size_t)bat0 * 64 + R + l15) * 256;
        const float* xr1 = x + ((size_t)bat1 * 64 + R + l15) * 256;
        #pragma unroll
        for (int t = 0; t < 8; ++t) {
            xaA[t] = cvt8(xr0 + t * 32 + quad * 8);
            xaB[t] = cvt8(xr1 + t * 32 + quad * 8);
        }
    }

    // ---------------- layer 1: out = relu(x@w1.T + b1) -> u_lds + oa --------
    layer2b<true, true>(xaA, xaB, wfA, nullptr, b1, u_lds, lane, quad, l15, R);
    bf16x8 oaA[8], oaB[8];
    #pragma unroll
    for (int t = 0; t < 8; ++t) {
        int off = ks_off(R + l15, t * 32 + quad * 8);
        oaA[t] = *(const bf16x8*)(u_lds + off);
        oaB[t] = *(const bf16x8*)(u_lds + 32768 + off);
    }

    // ---- qb[i] = out[i,:]·v + s0, parked in LDS (row = R + l15) ----
    {
        float qbA = flt[1540], qbB = qbA;
        const float* vvec = flt + 256;
        #pragma unroll
        for (int t = 0; t < 8; ++t) {
            f32x4 va = *(const f32x4*)(vvec + t * 32 + quad * 8);
            f32x4 vb = *(const f32x4*)(vvec + t * 32 + quad * 8 + 4);
            qbA += (float)oaA[t][0]*va[0] + (float)oaA[t][1]*va[1]
                 + (float)oaA[t][2]*va[2] + (float)oaA[t][3]*va[3]
                 + (float)oaA[t][4]*vb[0] + (float)oaA[t][5]*vb[1]
                 + (float)oaA[t][6]*vb[2] + (float)oaA[t][7]*vb[3];
            qbB += (float)oaB[t][0]*va[0] + (float)oaB[t][1]*va[1]
                 + (float)oaB[t][2]*va[2] + (float)oaB[t][3]*va[3]
                 + (float)oaB[t][4]*vb[0] + (float)oaB[t][5]*vb[1]
                 + (float)oaB[t][6]*vb[2] + (float)oaB[t][7]*vb[3];
        }
        qbA += __shfl_xor(qbA, 16);  qbA += __shfl_xor(qbA, 32);
        qbB += __shfl_xor(qbB, 16);  qbB += __shfl_xor(qbB, 32);
        if (lane < 16) {             // lane l holds qb for row R + l
            qbLDS[0][R + lane] = qbA;
            qbLDS[1][R + lane] = qbB;
        }
    }

    // first fused wA prefetch hoisted above the barrier (global-only dep)
    bf16x8 wA[4], wB[4];
    #pragma unroll
    for (int t = 0; t < 4; ++t)
        wA[t] = wfrag<true>(wfM, nullptr, 0, t, lane);

    __syncthreads();   // #1: both out-buffers complete across all waves

    // ------- fused q2 (= out@M + c2) + logits (= q2@out^T) ------------------
    f32x4 laA[4], laB[4];
    #pragma unroll
    for (int n = 0; n < 4; ++n) {
        laA[n] = (f32x4){0.f,0.f,0.f,0.f};
        laB[n] = (f32x4){0.f,0.f,0.f,0.f};
    }
    {
        bf16_t* qsA = &qscr[wv][0][0];
        bf16_t* qsB = &qscr[wv][1][0];

        #pragma unroll
        for (int t8 = 0; t8 < 8; ++t8) {
            const int n0 = 2 * t8, n1 = n0 + 1;

            // ---- q2 tile n0 ----
            #pragma unroll
            for (int t = 0; t < 4; ++t)
                wB[t] = wfrag<true>(wfM, nullptr, n0, 4 + t, lane);
            {
                f32x4 cA0 = {0.f,0.f,0.f,0.f}, cA1 = {0.f,0.f,0.f,0.f};
                f32x4 cB0 = {0.f,0.f,0.f,0.f}, cB1 = {0.f,0.f,0.f,0.f};
                __builtin_amdgcn_s_setprio(1);
                cA0 = MFMA(oaA[0], wA[0], cA0);  cB0 = MFMA(oaB[0], wA[0], cB0);
                cA1 = MFMA(oaA[1], wA[1], cA1);  cB1 = MFMA(oaB[1], wA[1], cB1);
                cA0 = MFMA(oaA[2], wA[2], cA0);  cB0 = MFMA(oaB[2], wA[2], cB0);
                cA1 = MFMA(oaA[3], wA[3], cA1);  cB1 = MFMA(oaB[3], wA[3], cB1);
                __builtin_amdgcn_s_setprio(0);
                #pragma unroll
                for (int t = 0; t < 4; ++t)
                    wA[t] = wfrag<true>(wfM, nullptr, n1, t, lane);
                __builtin_amdgcn_s_setprio(1);
                cA0 = MFMA(oaA[4], wB[0], cA0);  cB0 = MFMA(oaB[4], wB[0], cB0);
                cA1 = MFMA(oaA[5], wB[1], cA1);  cB1 = MFMA(oaB[5], wB[1], cB1);
                cA0 = MFMA(oaA[6], wB[2], cA0);  cB0 = MFMA(oaB[6], wB[2], cB0);
                cA1 = MFMA(oaA[7], wB[3], cA1);  cB1 = MFMA(oaB[7], wB[3], cB1);
                __builtin_amdgcn_s_setprio(0);
                f32x4 sA = cA0 + cA1, sB = cB0 + cB1;
                float bv = flt[n0 * 16 + l15];           // c2
                #pragma unroll
                for (int r2 = 0; r2 < 4; ++r2) {
                    int qo = (quad * 4 + r2) * 40 + l15;
                    qsA[qo] = (bf16_t)(sA[r2] + bv);
                    qsB[qo] = (bf16_t)(sB[r2] + bv);
                }
            }

            // ---- q2 tile n1 ----
            #pragma unroll
            for (int t = 0; t < 4; ++t)
                wB[t] = wfrag<true>(wfM, nullptr, n1, 4 + t, lane);
            {
                f32x4 cA0 = {0.f,0.f,0.f,0.f}, cA1 = {0.f,0.f,0.f,0.f};
                f32x4 cB0 = {0.f,0.f,0.f,0.f}, cB1 = {0.f,0.f,0.f,0.f};
                __builtin_amdgcn_s_setprio(1);
                cA0 = MFMA(oaA[0], wA[0], cA0);  cB0 = MFMA(oaB[0], wA[0], cB0);
                cA1 = MFMA(oaA[1], wA[1], cA1);  cB1 = MFMA(oaB[1], wA[1], cB1);
                cA0 = MFMA(oaA[2], wA[2], cA0);  cB0 = MFMA(oaB[2], wA[2], cB0);
                cA1 = MFMA(oaA[3], wA[3], cA1);  cB1 = MFMA(oaB[3], wA[3], cB1);
                __builtin_amdgcn_s_setprio(0);
                if (t8 < 7) {
                    #pragma unroll
                    for (int t = 0; t < 4; ++t)
                        wA[t] = wfrag<true>(wfM, nullptr, n0 + 2, t, lane);
                }
                __builtin_amdgcn_s_setprio(1);
                cA0 = MFMA(oaA[4], wB[0], cA0);  cB0 = MFMA(oaB[4], wB[0], cB0);
                cA1 = MFMA(oaA[5], wB[1], cA1);  cB1 = MFMA(oaB[5], wB[1], cB1);
                cA0 = MFMA(oaA[6], wB[2], cA0);  cB0 = MFMA(oaB[6], wB[2], cB0);
                cA1 = MFMA(oaA[7], wB[3], cA1);  cB1 = MFMA(oaB[7], wB[3], cB1);
                __builtin_amdgcn_s_setprio(0);
                f32x4 sA = cA0 + cA1, sB = cB0 + cB1;
                float bv = flt[n1 * 16 + l15];           // c2
                #pragma unroll
                for (int r2 = 0; r2 < 4; ++r2) {
                    int qo = (quad * 4 + r2) * 40 + 16 + l15;
                    qsA[qo] = (bf16_t)(sA[r2] + bv);
                    qsB[qo] = (bf16_t)(sB[r2] + bv);
                }
            }

            // ---- read q2 slice (A-operand order), 8 logits MFMAs vs out ----
            bf16x8 qaA = *(const bf16x8*)(qsA + l15 * 40 + quad * 8);
            bf16x8 qaB = *(const bf16x8*)(qsB + l15 * 40 + quad * 8);
            __builtin_amdgcn_s_setprio(1);
            #pragma unroll
            for (int np = 0; np < 4; ++np) {
                int ko = ks_off(np * 16 + l15, t8 * 32 + quad * 8);
                bf16x8 kA = *(const bf16x8*)(u_lds + ko);
                bf16x8 kB = *(const bf16x8*)(u_lds + 32768 + ko);
                laA[np] = MFMA(qaA, kA, laA[np]);
                laB[np] = MFMA(qaB, kB, laB[np]);
            }
            __builtin_amdgcn_s_setprio(0);
        }
    }

    // ---- per-row qb (row = R + quad*4 + r2; same-wave LDS, barrier #1 past)
    float qbra[4], qbrb[4];
    #pragma unroll
    for (int r2 = 0; r2 < 4; ++r2) {
        qbra[r2] = qbLDS[0][R + quad * 4 + r2];
        qbrb[r2] = qbLDS[1][R + quad * 4 + r2];
    }

    // ---------------- promo: offs[p][s] = w4p[p]·out[56+s] + pb[p] ----------
    {
        int s = lane >> 3, seg = lane & 7;     // wave wv handles p = wv
        const float* wrow = flt + 512 + wv * 256;
        #pragma unroll
        for (int b = 0; b < 2; ++b) {
            const unsigned char* kb = u_lds + b * 32768;
            float p = 0.f;
            #pragma unroll
            for (int m = 0; m < 4; ++m) {
                bf16x8 kv = *(const bf16x8*)(kb + ks_off(56 + s, seg * 32 + m * 8));
                f32x4 wa = *(const f32x4*)(wrow + seg * 32 + m * 8);
                f32x4 wb = *(const f32x4*)(wrow + seg * 32 + m * 8 + 4);
                p += (float)kv[0] * wa[0] + (float)kv[1] * wa[1]
                   + (float)kv[2] * wa[2] + (float)kv[3] * wa[3]
                   + (float)kv[4] * wb[0] + (float)kv[5] * wb[1]
                   + (float)kv[6] * wb[2] + (float)kv[7] * wb[3];
            }
            p += __shfl_down(p, 4);
            p += __shfl_down(p, 2);
            p += __shfl_down(p, 1);
            if (seg == 0) promoLDS[b][wv][s] = p + flt[1536 + wv];   // + pb[p]
        }
    }

    // wave 3 stages the logits[48:56, 56:64] patch (incl. qb!)
    if (wv == 3 && quad < 2 && l15 >= 8) {
        #pragma unroll
        for (int r2 = 0; r2 < 4; ++r2) {
            patchLDS[0][quad * 4 + r2][l15 - 8] = (laA[3][r2] + qbra[r2]) * PSCALE;
            patchLDS[1][quad * 4 + r2][l15 - 8] = (laB[3][r2] + qbrb[r2]) * PSCALE;
        }
    }

    __syncthreads();   // #2: everyone done READING out; promoLDS/patch ready

    // ---------------- fullbuf (aliased over out regions) --------------------
    float* fb0 = (float*)u_lds;
    float* fb1 = (float*)(u_lds + 32768);
    #pragma unroll
    for (int n = 0; n < 4; ++n) {
        #pragma unroll
        for (int r2 = 0; r2 < 4; ++r2) {
            int idx = (R + quad * 4 + r2) * 64 + n * 16 + l15;
            fb0[idx] = (laA[n][r2] + qbra[r2]) * PSCALE;
            fb1[idx] = (laB[n][r2] + qbrb[r2]) * PSCALE;
        }
    }

    // promo rows 64..66
    if (tid < 192) {
        int u = tid >> 6, vv2 = tid & 63;
        int mm = u * 64 + vv2;
        int r_ = mm / 24, c_ = mm - r_ * 24;
        int c3 = c_ / 3, cp = c_ - c3 * 3;
        fb0[(64 + u) * 64 + vv2] =
            promoLDS[0][cp][c3] + promoLDS[0][3][c3] + patchLDS[0][r_][c3];
        fb1[(64 + u) * 64 + vv2] =
            promoLDS[1][cp][c3] + promoLDS[1][3][c3] + patchLDS[1][r_][c3];
    }

    __syncthreads();   // #3: fullbufs ready

    // ---------------- gather ------------------------------------------------
    {
        float* orow0 = out + (size_t)bat0 * NPOL;
        float* orow1 = out + (size_t)(bat0 + 1) * NPOL;
        int   idxv[8];
        float v0[8], v1[8];
        #pragma unroll
        for (int i = 0; i < 8; ++i) {
            int g = tid + i * 256;
            idxv[i] = (g < NPOL) ? gidx[g] : 0;
        }
        #pragma unroll
        for (int i = 0; i < 8; ++i) {
            v0[i] = fb0[idxv[i]];
            v1[i] = fb1[idxv[i]];
        }
        #pragma unroll
        for (int i = 0; i < 8; ++i) {
            int g = tid + i * 256;
            if (g < NPOL) {
                orow0[g] = v0[i];
                if (has1) orow1[g] = v1[i];
            }
        }
    }
}

// ---------------- fallback kernel (no-workspace path, R9 structure) ---------
__global__ __launch_bounds__(256, 2)
void policy_main(const float* __restrict__ x,
                 const float* __restrict__ w1,
                 const float* __restrict__ w2,
                 const float* __restrict__ w3,
                 const float* __restrict__ b1,
                 const float* __restrict__ b2,
                 const float* __restrict__ b3,
                 const float* __restrict__ w4,
                 const int*   __restrict__ gidx,
                 float* __restrict__ out,
                 int nbat) {
    __shared__ __align__(16) unsigned char u_lds[2 * 32768];
    __shared__ __align__(16) bf16_t qscr[4][2][16 * 40];
    __shared__ float promoLDS[2][4][8];
    __shared__ float patchLDS[2][8][8];

    const int tid  = threadIdx.x;
    const int lane = tid & 63;
    const int wv   = tid >> 6;
    const int quad = lane >> 4;
    const int l15  = lane & 15;
    const int R    = wv * 16;

    const int bat0 = blockIdx.x * 2;
    const bool has1 = (bat0 + 1) < nbat;
    const int bat1 = has1 ? bat0 + 1 : bat0;

    bf16x8 xaA[8], xaB[8];
    {
        const float* xr0 = x + ((size_t)bat0 * 64 + R + l15) * 256;
        const float* xr1 = x + ((size_t)bat1 * 64 + R + l15) * 256;
        #pragma unroll
        for (int t = 0; t < 8; ++t) {
            xaA[t] = cvt8(xr0 + t * 32 + quad * 8);
            xaB[t] = cvt8(xr1 + t * 32 + quad * 8);
        }
    }

    layer2b<false, true>(xaA, xaB, nullptr, w1, b1, u_lds, lane, quad, l15, R);
    bf16x8 oaA[8], oaB[8];
    #pragma unroll
    for (int t = 0; t < 8; ++t) {
        int off = ks_off(R + l15, t * 32 + quad * 8);
        oaA[t] = *(const bf16x8*)(u_lds + off);
        oaB[t] = *(const bf16x8*)(u_lds + 32768 + off);
    }

    layer2b<false, false>(oaA, oaB, nullptr, w3, b3, u_lds, lane, quad, l15, R);

    __syncthreads();

    f32x4 laA[4], laB[4];
    #pragma unroll
    for (int n = 0; n < 4; ++n) {
        laA[n] = (f32x4){0.f,0.f,0.f,0.f};
        laB[n] = (f32x4){0.f,0.f,0.f,0.f};
    }
    {
        bf16_t* qsA = &qscr[wv][0][0];
        bf16_t* qsB = &qscr[wv][1][0];
        bf16x8 wA[4], wB[4];
        #pragma unroll
        for (int t = 0; t < 4; ++t)
            wA[t] = wfrag<false>(nullptr, w2, 0, t, lane);

        #pragma unroll
        for (int t8 = 0; t8 < 8; ++t8) {
            const int n0 = 2 * t8, n1 = n0 + 1;
            #pragma unroll
            for (int t = 0; t < 4; ++t)
                wB[t] = wfrag<false>(nullptr, w2, n0, 4 + t, lane);
            {
                f32x4 cA0 = {0.f,0.f,0.f,0.f}, cA1 = {0.f,0.f,0.f,0.f};
                f32x4 cB0 = {0.f,0.f,0.f,0.f}, cB1 = {0.f,0.f,0.f,0.f};
                cA0 = MFMA(oaA[0], wA[0], cA0);  cB0 = MFMA(oaB[0], wA[0], cB0);
                cA1 = MFMA(oaA[1], wA[1], cA1);  cB1 = MFMA(oaB[1], wA[1], cB1);
                cA0 = MFMA(oaA[2], wA[2], cA0);  cB0 = MFMA(oaB[2], wA[2], cB0);
                cA1 = MFMA(oaA[3], wA[3], cA1);  cB1 = MFMA(oaB[3], wA[3], cB1);
                #pragma unroll
                for (int t = 0; t < 4; ++t)
                    wA[t] = wfrag<false>(nullptr, w2, n1, t, lane);
                cA0 = MFMA(oaA[4], wB[0], cA0);  cB0 = MFMA(oaB[4], wB[0], cB0);
                cA1 = MFMA(oaA[5], wB[1], cA1);  cB1 = MFMA(oaB[5], wB[1], cB1);
                cA0 = MFMA(oaA[6], wB[2], cA0);  cB0 = MFMA(oaB[6], wB[2], cB0);
                cA1 = MFMA(oaA[7], wB[3], cA1);  cB1 = MFMA(oaB[7], wB[3], cB1);
                f32x4 sA = cA0 + cA1, sB = cB0 + cB1;
                float bv = b2[n0 * 16 + l15];
                #pragma unroll
                for (int r2 = 0; r2 < 4; ++r2) {
                    int qo = (quad * 4 + r2) * 40 + l15;
                    qsA[qo] = (bf16_t)(sA[r2] + bv);
                    qsB[qo] = (bf16_t)(sB[r2] + bv);
                }
            }
            #pragma unroll
            for (int t = 0; t < 4; ++t)
                wB[t] = wfrag<false>(nullptr, w2, n1, 4 + t, lane);
            {
                f32x4 cA0 = {0.f,0.f,0.f,0.f}, cA1 = {0.f,0.f,0.f,0.f};
                f32x4 cB0 = {0.f,0.f,0.f,0.f}, cB1 = {0.f,0.f,0.f,0.f};
                cA0 = MFMA(oaA[0], wA[0], cA0);  cB0 = MFMA(oaB[0], wA[0], cB0);
                cA1 = MFMA(oaA[1], wA[1], cA1);  cB1 = MFMA(oaB[1], wA[1], cB1);
                cA0 = MFMA(oaA[2], wA[2], cA0);  cB0 = MFMA(oaB[2], wA[2], cB0);
                cA1 = MFMA(oaA[3], wA[3], cA1);  cB1 = MFMA(oaB[3], wA[3], cB1);
                if (t8 < 7) {
                    #pragma unroll
                    for (int t = 0; t < 4; ++t)
                        wA[t] = wfrag<false>(nullptr, w2, n0 + 2, t, lane);
                }
                cA0 = MFMA(oaA[4], wB[0], cA0);  cB0 = MFMA(oaB[4], wB[0], cB0);
                cA1 = MFMA(oaA[5], wB[1], cA1);  cB1 = MFMA(oaB[5], wB[1], cB1);
                cA0 = MFMA(oaA[6], wB[2], cA0);  cB0 = MFMA(oaB[6], wB[2], cB0);
                cA1 = MFMA(oaA[7], wB[3], cA1);  cB1 = MFMA(oaB[7], wB[3], cB1);
                f32x4 sA = cA0 + cA1, sB = cB0 + cB1;
                float bv = b2[n1 * 16 + l15];
                #pragma unroll
                for (int r2 = 0; r2 < 4; ++r2) {
                    int qo = (quad * 4 + r2) * 40 + 16 + l15;
                    qsA[qo] = (bf16_t)(sA[r2] + bv);
                    qsB[qo] = (bf16_t)(sB[r2] + bv);
                }
            }
            bf16x8 qaA = *(const bf16x8*)(qsA + l15 * 40 + quad * 8);
            bf16x8 qaB = *(const bf16x8*)(qsB + l15 * 40 + quad * 8);
            #pragma unroll
            for (int np = 0; np < 4; ++np) {
                int ko = ks_off(np * 16 + l15, t8 * 32 + quad * 8);
                bf16x8 kA = *(const bf16x8*)(u_lds + ko);
                bf16x8 kB = *(const bf16x8*)(u_lds + 32768 + ko);
                laA[np] = MFMA(qaA, kA, laA[np]);
                laB[np] = MFMA(qaB, kB, laB[np]);
            }
        }
    }

    {
        int s = lane >> 3, seg = lane & 7;
        const float* wrow = w4 + wv * 256;
        #pragma unroll
        for (int b = 0; b < 2; ++b) {
            const unsigned char* kb = u_lds + b * 32768;
            float p = 0.f;
            #pragma unroll
            for (int m = 0; m < 4; ++m) {
                bf16x8 kv = *(const bf16x8*)(kb + ks_off(56 + s, seg * 32 + m * 8));
                f32x4 wa = *(const f32x4*)(wrow + seg * 32 + m * 8);
                f32x4 wb = *(const f32x4*)(wrow + seg * 32 + m * 8 + 4);
                p += (float)kv[0] * wa[0] + (float)kv[1] * wa[1]
                   + (float)kv[2] * wa[2] + (float)kv[3] * wa[3]
                   + (float)kv[4] * wb[0] + (float)kv[5] * wb[1]
                   + (float)kv[6] * wb[2] + (float)kv[7] * wb[3];
            }
            p += __shfl_down(p, 4);
            p += __shfl_down(p, 2);
            p += __shfl_down(p, 1);
            if (seg == 0) promoLDS[b][wv][s] = p;
        }
    }

    if (wv == 3 && quad < 2 && l15 >= 8) {
        #pragma unroll
        for (int r2 = 0; r2 < 4; ++r2) {
            patchLDS[0][quad * 4 + r2][l15 - 8] = laA[3][r2] * PSCALE;
            patchLDS[1][quad * 4 + r2][l15 - 8] = laB[3][r2] * PSCALE;
        }
    }

    __syncthreads();

    float* fb0 = (float*)u_lds;
    float* fb1 = (float*)(u_lds + 32768);
    #pragma unroll
    for (int n = 0; n < 4; ++n) {
        #pragma unroll
        for (int r2 = 0; r2 < 4; ++r2) {
            int idx = (R + quad * 4 + r2) * 64 + n * 16 + l15;
            fb0[idx] = laA[n][r2] * PSCALE;
            fb1[idx] = laB[n][r2] * PSCALE;
        }
    }

    if (tid < 192) {
        int u = tid >> 6, vv2 = tid & 63;
        int mm = u * 64 + vv2;
        int r_ = mm / 24, c_ = mm - r_ * 24;
        int c3 = c_ / 3, cp = c_ - c3 * 3;
        fb0[(64 + u) * 64 + vv2] =
            promoLDS[0][cp][c3] + promoLDS[0][3][c3] + patchLDS[0][r_][c3];
        fb1[(64 + u) * 64 + vv2] =
            promoLDS[1][cp][c3] + promoLDS[1][3][c3] + patchLDS[1][r_][c3];
    }

    __syncthreads();

    {
        float* orow0 = out + (size_t)bat0 * NPOL;
        float* orow1 = out + (size_t)(bat0 + 1) * NPOL;
        int   idxv[8];
        float v0[8], v1[8];
        #pragma unroll
        for (int i = 0; i < 8; ++i) {
            int g = tid + i * 256;
            idxv[i] = (g < NPOL) ? gidx[g] : 0;
        }
        #pragma unroll
        for (int i = 0; i < 8; ++i) {
            v0[i] = fb0[idxv[i]];
            v1[i] = fb1[idxv[i]];
        }
        #pragma unroll
        for (int i = 0; i < 8; ++i) {
            int g = tid + i * 256;
            if (g < NPOL) {
                orow0[g] = v0[i];
                if (has1) orow1[g] = v1[i];
            }
        }
    }
}

extern "C" void kernel_launch(void* const* d_in, const int* in_sizes, int n_in,
                              void* d_out, int out_size, void* d_ws, size_t ws_size,
                              hipStream_t stream) {
    const float* x    = (const float*)d_in[0];
    const float* w1   = (const float*)d_in[1];
    const float* b1   = (const float*)d_in[2];
    const float* w2   = (const float*)d_in[3];
    const float* b2   = (const float*)d_in[4];
    const float* w3   = (const float*)d_in[5];
    const float* b3   = (const float*)d_in[6];
    const float* w4   = (const float*)d_in[7];
    const int*   gidx = (const int*)d_in[8];
    float* out = (float*)d_out;

    int nbat = in_sizes[0] / (64 * 256);        // 4096
    int nblk = (nbat + 1) / 2;
    const size_t ws_needed = 262144 + 8192;     // wfA+wfM (256K) + float region

    if (ws_size >= ws_needed) {
        bf16_t* wfA = (bf16_t*)d_ws;
        bf16_t* wfM = wfA + 65536;
        float*  flt = (float*)((char*)d_ws + 262144);
        prep_w1  <<<256, 256, 0, stream>>>(w1, wfA);
        prep_mat <<<256, 256, 0, stream>>>(w2, w3, wfM);
        prep_vecs<<<1,   256, 0, stream>>>(w2, w3, b2, b3, w4, flt);
        policy_fused<<<nblk, 256, 0, stream>>>(
            x, wfA, wfM, flt, b1, gidx, out, nbat);
    } else {
        policy_main<<<nblk, 256, 0, stream>>>(
            x, w1, w2, w3, b1, b2, b3, w4, gidx, out, nbat);
    }
}

// Round 13
// 469.261 us; speedup vs baseline: 1.1424x; 1.0740x over previous
//
#include <hip/hip_runtime.h>

// PolicyHead fused kernel, R15 = R14 main kernel (converged, ~187us) +
// prep overhaul. R14 post-mortem: main kernel at its latency floor
// (R9..R14 all 185-187; stall-points x 128-arch-reg wall invariant; every
// structural escape R10-R13 regressed). NEW lever: e2e-minus-kernel
// overhead jumped 240 -> 317us exactly when prep_mat/prep_vecs appeared
// (R8->R9). prep_vecs is a SINGLE 256-thread block with serial tail loops
// (~30-40us on one CU) and we pay 4 launches.
// R15: one wide prep kernel (520 blocks: w1-frags | M | vecs-partials
// h-split 8 ways) + tiny fold kernel (reductions, pb, s0). 4 launches -> 3.
// Main kernel byte-identical to R14 (VGPR 96, WRITE == output, 0 spills).

typedef __bf16 bf16_t;
typedef __bf16 bf16x8 __attribute__((ext_vector_type(8)));
typedef float  f32x4  __attribute__((ext_vector_type(4)));

#define PSCALE 0.0625f
#define NPOL   1858
#define MFMA(a,b,c) __builtin_amdgcn_mfma_f32_16x16x32_bf16(a, b, c, 0, 0, 0)

// ---------------- prep kernels (ws path) ----------------
// ws layout: [0,128K) wfA = w1 frags bf16; [128K,256K) wfM = M frags bf16;
// [256K, 256K+8K) flt: c2[256]|v[256]|w4p[4][256]|pb[4]|s0;
// [264K, 264K+48K) pscr: [8 hblk][6 val][256 m] partial sums.

__global__ void prep_all(const float* __restrict__ w1,
                         const float* __restrict__ w2,
                         const float* __restrict__ w3,
                         const float* __restrict__ w4,
                         const float* __restrict__ b2,
                         const float* __restrict__ b3,
                         bf16_t* __restrict__ wfA,
                         bf16_t* __restrict__ wfM,
                         float* __restrict__ pscr) {
    const int b = blockIdx.x, tid = threadIdx.x;
    if (b < 256) {
        // ---- w1 -> B-fragment layout ----
        int i = b * 256 + tid;
        int j = i & 7, lane = (i >> 3) & 63, t = (i >> 9) & 7, n = (i >> 12) & 15;
        int row = n * 16 + (lane & 15);          // output-col (w1 row)
        int col = t * 32 + (lane >> 4) * 8 + j;  // k index
        wfA[i] = (bf16_t)w1[row * 256 + col];
    } else if (b < 512) {
        // ---- M[m1][m2] = sum_h w2[h][m1]*w3[h][m2], frag layout ----
        int m1 = b - 256, m2 = tid;
        float acc = 0.f;
        #pragma unroll 8
        for (int h = 0; h < 256; ++h)
            acc += w2[h * 256 + m1] * w3[h * 256 + m2];
        int t = m1 >> 5, quad = (m1 >> 3) & 3, j = m1 & 7;
        int n = m2 >> 4, l15 = m2 & 15;
        wfM[(((n * 8 + t) * 64) + (quad * 16 + l15)) * 8 + j] = (bf16_t)acc;
    } else {
        // ---- vecs partials: h-block jj, thread m ----
        int jj = b - 512;                        // 0..7
        int m = tid;
        float c2 = 0.f, vv = 0.f, p0 = 0.f, p1 = 0.f, p2 = 0.f, p3 = 0.f;
        const int h0 = jj * 32;
        #pragma unroll 8
        for (int h = h0; h < h0 + 32; ++h) {
            float w3h = w3[h * 256 + m];
            c2 += b2[h] * w3h;
            p0 += w4[h] * w3h;
            p1 += w4[256 + h] * w3h;
            p2 += w4[512 + h] * w3h;
            p3 += w4[768 + h] * w3h;
            vv += w2[h * 256 + m] * b3[h];
        }
        float* base = pscr + (size_t)jj * 6 * 256;
        base[0 * 256 + m] = c2;
        base[1 * 256 + m] = vv;
        base[2 * 256 + m] = p0;
        base[3 * 256 + m] = p1;
        base[4 * 256 + m] = p2;
        base[5 * 256 + m] = p3;
    }
}

__global__ void prep_fold(const float* __restrict__ w4,
                          const float* __restrict__ b2,
                          const float* __restrict__ b3,
                          const float* __restrict__ pscr,
                          float* __restrict__ flt) {
    const int m = threadIdx.x;
    float s0v = 0.f, s1v = 0.f, s2v = 0.f, s3v = 0.f, s4v = 0.f, s5v = 0.f;
    #pragma unroll
    for (int j = 0; j < 8; ++j) {
        const float* base = pscr + (size_t)j * 6 * 256;
        s0v += base[0 * 256 + m];
        s1v += base[1 * 256 + m];
        s2v += base[2 * 256 + m];
        s3v += base[3 * 256 + m];
        s4v += base[4 * 256 + m];
        s5v += base[5 * 256 + m];
    }
    flt[m]        = s0v;   // c2
    flt[256 + m]  = s1v;   // v
    flt[512 + m]  = s2v;   // w4p[0]
    flt[768 + m]  = s3v;
    flt[1024 + m] = s4v;
    flt[1280 + m] = s5v;

    // pb[0..3] and s0 via LDS reduce
    __shared__ float red[5][256];
    float b3m = b3[m];
    red[0][m] = w4[m]       * b3m;
    red[1][m] = w4[256 + m] * b3m;
    red[2][m] = w4[512 + m] * b3m;
    red[3][m] = w4[768 + m] * b3m;
    red[4][m] = b2[m] * b3m;
    __syncthreads();
    if (m < 5) {
        float a = 0.f;
        for (int h = 0; h < 256; ++h) a += red[m][h];
        flt[1536 + m] = a;   // m<4: pb[m]; m==4 -> flt[1540] = s0
    }
}

// ---------------- shared device helpers ----------------

template <bool USE_WS>
__device__ __forceinline__ bf16x8 wfrag(const bf16_t* __restrict__ wl,
                                        const float* __restrict__ w,
                                        int n, int t, int lane) {
    if constexpr (USE_WS) {
        return *(const bf16x8*)(wl + (((n * 8 + t) * 64 + lane) << 3));
    } else {
        int l15 = lane & 15, quad = lane >> 4;
        const float* p = w + (n * 16 + l15) * 256 + t * 32 + quad * 8;
        f32x4 lo = *(const f32x4*)p;
        f32x4 hi = *(const f32x4*)(p + 4);
        bf16x8 v;
        v[0] = (bf16_t)lo[0]; v[1] = (bf16_t)lo[1];
        v[2] = (bf16_t)lo[2]; v[3] = (bf16_t)lo[3];
        v[4] = (bf16_t)hi[0]; v[5] = (bf16_t)hi[1];
        v[6] = (bf16_t)hi[2]; v[7] = (bf16_t)hi[3];
        return v;
    }
}

// Swizzled byte offset into a 64x256 bf16 buffer (32768 B).
__device__ __forceinline__ int ks_off(int row, int col) {
    return ((row << 9) + (col << 1)) ^ ((row & 7) << 4);
}

__device__ __forceinline__ bf16x8 cvt8(const float* __restrict__ p) {
    f32x4 lo = *(const f32x4*)p;
    f32x4 hi = *(const f32x4*)(p + 4);
    bf16x8 v;
    v[0] = (bf16_t)lo[0]; v[1] = (bf16_t)lo[1];
    v[2] = (bf16_t)lo[2]; v[3] = (bf16_t)lo[3];
    v[4] = (bf16_t)hi[0]; v[5] = (bf16_t)hi[1];
    v[6] = (bf16_t)hi[2]; v[7] = (bf16_t)hi[3];
    return v;
}

// Full 256->256 layer, both batches, half-tile (4-frag) weight prefetch.
// setprio(1) while the MFMA cluster runs; (0) while issuing loads/stores.
template <bool USE_WS, bool RELU>
__device__ __forceinline__ void layer2b(const bf16x8* inA, const bf16x8* inB,
                                        const bf16_t* __restrict__ wl,
                                        const float* __restrict__ wraw,
                                        const float* __restrict__ bias,
                                        unsigned char* __restrict__ u_lds,
                                        int lane, int quad, int l15, int R) {
    bf16x8 wA[4], wB[4];
    #pragma unroll
    for (int t = 0; t < 4; ++t)
        wA[t] = wfrag<USE_WS>(wl, wraw, 0, t, lane);

    #pragma unroll
    for (int n = 0; n < 16; ++n) {
        #pragma unroll
        for (int t = 0; t < 4; ++t)
            wB[t] = wfrag<USE_WS>(wl, wraw, n, 4 + t, lane);

        f32x4 aA0 = {0.f,0.f,0.f,0.f}, aA1 = {0.f,0.f,0.f,0.f};
        f32x4 aB0 = {0.f,0.f,0.f,0.f}, aB1 = {0.f,0.f,0.f,0.f};
        __builtin_amdgcn_s_setprio(1);
        aA0 = MFMA(inA[0], wA[0], aA0);  aB0 = MFMA(inB[0], wA[0], aB0);
        aA1 = MFMA(inA[1], wA[1], aA1);  aB1 = MFMA(inB[1], wA[1], aB1);
        aA0 = MFMA(inA[2], wA[2], aA0);  aB0 = MFMA(inB[2], wA[2], aB0);
        aA1 = MFMA(inA[3], wA[3], aA1);  aB1 = MFMA(inB[3], wA[3], aB1);
        __builtin_amdgcn_s_setprio(0);

        if (n < 15) {
            #pragma unroll
            for (int t = 0; t < 4; ++t)
                wA[t] = wfrag<USE_WS>(wl, wraw, n + 1, t, lane);
        }

        __builtin_amdgcn_s_setprio(1);
        aA0 = MFMA(inA[4], wB[0], aA0);  aB0 = MFMA(inB[4], wB[0], aB0);
        aA1 = MFMA(inA[5], wB[1], aA1);  aB1 = MFMA(inB[5], wB[1], aB1);
        aA0 = MFMA(inA[6], wB[2], aA0);  aB0 = MFMA(inB[6], wB[2], aB0);
        aA1 = MFMA(inA[7], wB[3], aA1);  aB1 = MFMA(inB[7], wB[3], aB1);
        __builtin_amdgcn_s_setprio(0);

        f32x4 sA = aA0 + aA1, sB = aB0 + aB1;
        float bv = bias[n * 16 + l15];
        #pragma unroll
        for (int r2 = 0; r2 < 4; ++r2) {
            int off = ks_off(R + quad * 4 + r2, n * 16 + l15);
            float vA = sA[r2] + bv, vB = sB[r2] + bv;
            if (RELU) { vA = fmaxf(vA, 0.f); vB = fmaxf(vB, 0.f); }
            *(bf16_t*)(u_lds + off)         = (bf16_t)vA;
            *(bf16_t*)(u_lds + 32768 + off) = (bf16_t)vB;
        }
    }
}

// ---------------- R15 main kernel (ws path) — identical to R14 --------------
__global__ __launch_bounds__(256, 2)
void policy_fused(const float* __restrict__ x,
                  const bf16_t* __restrict__ wfA,
                  const bf16_t* __restrict__ wfM,
                  const float* __restrict__ flt,   // c2|v|w4p|pb|s0
                  const float* __restrict__ b1,
                  const int*   __restrict__ gidx,
                  float* __restrict__ out,
                  int nbat) {
    // Two 32768 B unions: phase A = out (64x256 bf16, XOR-swizzled) per batch;
    //                     phase B = fullbuf (67x64 f32) per batch.
    __shared__ __align__(16) unsigned char u_lds[2 * 32768];
    __shared__ __align__(16) bf16_t qscr[4][2][16 * 40];  // per-wave q2 transpose
    __shared__ float promoLDS[2][4][8];
    __shared__ float patchLDS[2][8][8];
    __shared__ float qbLDS[2][64];

    const int tid  = threadIdx.x;
    const int lane = tid & 63;
    const int wv   = tid >> 6;
    const int quad = lane >> 4;
    const int l15  = lane & 15;
    const int R    = wv * 16;

    const int bat0 = blockIdx.x * 2;
    const bool has1 = (bat0 + 1) < nbat;
    const int bat1 = has1 ? bat0 + 1 : bat0;

    // ---- x A-fragments ----
    bf16x8 xaA[8], xaB[8];
    {
        const float* xr0 = x + ((size_t)bat0 * 64 + R + l15) * 256;
        const float* xr1 = x + ((size_t)bat1 * 64 + R + l15) * 256;
        #pragma unroll
        for (int t = 0; t < 8; ++t) {
            xaA[t] = cvt8(xr0 + t * 32 + quad * 8);
            xaB[t] = cvt8(xr1 + t * 32 + quad * 8);
        }
    }

    // ---------------- layer 1: out = relu(x@w1.T + b1) -> u_lds + oa --------
    layer2b<true, true>(xaA, xaB, wfA, nullptr, b1, u_lds, lane, quad, l15, R);
    bf16x8 oaA[8], oaB[8];
    #pragma unroll
    for (int t = 0; t < 8; ++t) {
        int off = ks_off(R + l15, t * 32 + quad * 8);
        oaA[t] = *(const bf16x8*)(u_lds + off);
        oaB[t] = *(const bf16x8*)(u_lds + 32768 + off);
    }

    // ---- qb[i] = out[i,:]·v + s0, parked in LDS (row = R + l15) ----
    {
        float qbA = flt[1540], qbB = qbA;
        const float* vvec = flt + 256;
        #pragma unroll
        for (int t = 0; t < 8; ++t) {
            f32x4 va = *(const f32x4*)(vvec + t * 32 + quad * 8);
            f32x4 vb = *(const f32x4*)(vvec + t * 32 + quad * 8 + 4);
            qbA += (float)oaA[t][0]*va[0] + (float)oaA[t][1]*va[1]
                 + (float)oaA[t][2]*va[2] + (float)oaA[t][3]*va[3]
                 + (float)oaA[t][4]*vb[0] + (float)oaA[t][5]*vb[1]
                 + (float)oaA[t][6]*vb[2] + (float)oaA[t][7]*vb[3];
            qbB += (float)oaB[t][0]*va[0] + (float)oaB[t][1]*va[1]
                 + (float)oaB[t][2]*va[2] + (float)oaB[t][3]*va[3]
                 + (float)oaB[t][4]*vb[0] + (float)oaB[t][5]*vb[1]
                 + (float)oaB[t][6]*vb[2] + (float)oaB[t][7]*vb[3];
        }
        qbA += __shfl_xor(qbA, 16);  qbA += __shfl_xor(qbA, 32);
        qbB += __shfl_xor(qbB, 16);  qbB += __shfl_xor(qbB, 32);
        if (lane < 16) {             // lane l holds qb for row R + l
            qbLDS[0][R + lane] = qbA;
            qbLDS[1][R + lane] = qbB;
        }
    }

    // first fused wA prefetch hoisted above the barrier (global-only dep)
    bf16x8 wA[4], wB[4];
    #pragma unroll
    for (int t = 0; t < 4; ++t)
        wA[t] = wfrag<true>(wfM, nullptr, 0, t, lane);

    __syncthreads();   // #1: both out-buffers complete across all waves

    // ------- fused q2 (= out@M + c2) + logits (= q2@out^T) ------------------
    f32x4 laA[4], laB[4];
    #pragma unroll
    for (int n = 0; n < 4; ++n) {
        laA[n] = (f32x4){0.f,0.f,0.f,0.f};
        laB[n] = (f32x4){0.f,0.f,0.f,0.f};
    }
    {
        bf16_t* qsA = &qscr[wv][0][0];
        bf16_t* qsB = &qscr[wv][1][0];

        #pragma unroll
        for (int t8 = 0; t8 < 8; ++t8) {
            const int n0 = 2 * t8, n1 = n0 + 1;

            // ---- q2 tile n0 ----
            #pragma unroll
            for (int t = 0; t < 4; ++t)
                wB[t] = wfrag<true>(wfM, nullptr, n0, 4 + t, lane);
            {
                f32x4 cA0 = {0.f,0.f,0.f,0.f}, cA1 = {0.f,0.f,0.f,0.f};
                f32x4 cB0 = {0.f,0.f,0.f,0.f}, cB1 = {0.f,0.f,0.f,0.f};
                __builtin_amdgcn_s_setprio(1);
                cA0 = MFMA(oaA[0], wA[0], cA0);  cB0 = MFMA(oaB[0], wA[0], cB0);
                cA1 = MFMA(oaA[1], wA[1], cA1);  cB1 = MFMA(oaB[1], wA[1], cB1);
                cA0 = MFMA(oaA[2], wA[2], cA0);  cB0 = MFMA(oaB[2], wA[2], cB0);
                cA1 = MFMA(oaA[3], wA[3], cA1);  cB1 = MFMA(oaB[3], wA[3], cB1);
                __builtin_amdgcn_s_setprio(0);
                #pragma unroll
                for (int t = 0; t < 4; ++t)
                    wA[t] = wfrag<true>(wfM, nullptr, n1, t, lane);
                __builtin_amdgcn_s_setprio(1);
                cA0 = MFMA(oaA[4], wB[0], cA0);  cB0 = MFMA(oaB[4], wB[0], cB0);
                cA1 = MFMA(oaA[5], wB[1], cA1);  cB1 = MFMA(oaB[5], wB[1], cB1);
                cA0 = MFMA(oaA[6], wB[2], cA0);  cB0 = MFMA(oaB[6], wB[2], cB0);
                cA1 = MFMA(oaA[7], wB[3], cA1);  cB1 = MFMA(oaB[7], wB[3], cB1);
                __builtin_amdgcn_s_setprio(0);
                f32x4 sA = cA0 + cA1, sB = cB0 + cB1;
                float bv = flt[n0 * 16 + l15];           // c2
                #pragma unroll
                for (int r2 = 0; r2 < 4; ++r2) {
                    int qo = (quad * 4 + r2) * 40 + l15;
                    qsA[qo] = (bf16_t)(sA[r2] + bv);
                    qsB[qo] = (bf16_t)(sB[r2] + bv);
                }
            }

            // ---- q2 tile n1 ----
            #pragma unroll
            for (int t = 0; t < 4; ++t)
                wB[t] = wfrag<true>(wfM, nullptr, n1, 4 + t, lane);
            {
                f32x4 cA0 = {0.f,0.f,0.f,0.f}, cA1 = {0.f,0.f,0.f,0.f};
                f32x4 cB0 = {0.f,0.f,0.f,0.f}, cB1 = {0.f,0.f,0.f,0.f};
                __builtin_amdgcn_s_setprio(1);
                cA0 = MFMA(oaA[0], wA[0], cA0);  cB0 = MFMA(oaB[0], wA[0], cB0);
                cA1 = MFMA(oaA[1], wA[1], cA1);  cB1 = MFMA(oaB[1], wA[1], cB1);
                cA0 = MFMA(oaA[2], wA[2], cA0);  cB0 = MFMA(oaB[2], wA[2], cB0);
                cA1 = MFMA(oaA[3], wA[3], cA1);  cB1 = MFMA(oaB[3], wA[3], cB1);
                __builtin_amdgcn_s_setprio(0);
                if (t8 < 7) {
                    #pragma unroll
                    for (int t = 0; t < 4; ++t)
                        wA[t] = wfrag<true>(wfM, nullptr, n0 + 2, t, lane);
                }
                __builtin_amdgcn_s_setprio(1);
                cA0 = MFMA(oaA[4], wB[0], cA0);  cB0 = MFMA(oaB[4], wB[0], cB0);
                cA1 = MFMA(oaA[5], wB[1], cA1);  cB1 = MFMA(oaB[5], wB[1], cB1);
                cA0 = MFMA(oaA[6], wB[2], cA0);  cB0 = MFMA(oaB[6], wB[2], cB0);
                cA1 = MFMA(oaA[7], wB[3], cA1);  cB1 = MFMA(oaB[7], wB[3], cB1);
                __builtin_amdgcn_s_setprio(0);
                f32x4 sA = cA0 + cA1, sB = cB0 + cB1;
                float bv = flt[n1 * 16 + l15];           // c2
                #pragma unroll
                for (int r2 = 0; r2 < 4; ++r2) {
                    int qo = (quad * 4 + r2) * 40 + 16 + l15;
                    qsA[qo] = (bf16_t)(sA[r2] + bv);
                    qsB[qo] = (bf16_t)(sB[r2] + bv);
                }
            }

            // ---- read q2 slice (A-operand order), 8 logits MFMAs vs out ----
            bf16x8 qaA = *(const bf16x8*)(qsA + l15 * 40 + quad * 8);
            bf16x8 qaB = *(const bf16x8*)(qsB + l15 * 40 + quad * 8);
            __builtin_amdgcn_s_setprio(1);
            #pragma unroll
            for (int np = 0; np < 4; ++np) {
                int ko = ks_off(np * 16 + l15, t8 * 32 + quad * 8);
                bf16x8 kA = *(const bf16x8*)(u_lds + ko);
                bf16x8 kB = *(const bf16x8*)(u_lds + 32768 + ko);
                laA[np] = MFMA(qaA, kA, laA[np]);
                laB[np] = MFMA(qaB, kB, laB[np]);
            }
            __builtin_amdgcn_s_setprio(0);
        }
    }

    // ---- per-row qb (row = R + quad*4 + r2; same-wave LDS, barrier #1 past)
    float qbra[4], qbrb[4];
    #pragma unroll
    for (int r2 = 0; r2 < 4; ++r2) {
        qbra[r2] = qbLDS[0][R + quad * 4 + r2];
        qbrb[r2] = qbLDS[1][R + quad * 4 + r2];
    }

    // ---------------- promo: offs[p][s] = w4p[p]·out[56+s] + pb[p] ----------
    {
        int s = lane >> 3, seg = lane & 7;     // wave wv handles p = wv
        const float* wrow = flt + 512 + wv * 256;
        #pragma unroll
        for (int b = 0; b < 2; ++b) {
            const unsigned char* kb = u_lds + b * 32768;
            float p = 0.f;
            #pragma unroll
            for (int m = 0; m < 4; ++m) {
                bf16x8 kv = *(const bf16x8*)(kb + ks_off(56 + s, seg * 32 + m * 8));
                f32x4 wa = *(const f32x4*)(wrow + seg * 32 + m * 8);
                f32x4 wb = *(const f32x4*)(wrow + seg * 32 + m * 8 + 4);
                p += (float)kv[0] * wa[0] + (float)kv[1] * wa[1]
                   + (float)kv[2] * wa[2] + (float)kv[3] * wa[3]
                   + (float)kv[4] * wb[0] + (float)kv[5] * wb[1]
                   + (float)kv[6] * wb[2] + (float)kv[7] * wb[3];
            }
            p += __shfl_down(p, 4);
            p += __shfl_down(p, 2);
            p += __shfl_down(p, 1);
            if (seg == 0) promoLDS[b][wv][s] = p + flt[1536 + wv];   // + pb[p]
        }
    }

    // wave 3 stages the logits[48:56, 56:64] patch (incl. qb!)
    if (wv == 3 && quad < 2 && l15 >= 8) {
        #pragma unroll
        for (int r2 = 0; r2 < 4; ++r2) {
            patchLDS[0][quad * 4 + r2][l15 - 8] = (laA[3][r2] + qbra[r2]) * PSCALE;
            patchLDS[1][quad * 4 + r2][l15 - 8] = (laB[3][r2] + qbrb[r2]) * PSCALE;
        }
    }

    __syncthreads();   // #2: everyone done READING out; promoLDS/patch ready

    // ---------------- fullbuf (aliased over out regions) --------------------
    float* fb0 = (float*)u_lds;
    float* fb1 = (float*)(u_lds + 32768);
    #pragma unroll
    for (int n = 0; n < 4; ++n) {
        #pragma unroll
        for (int r2 = 0; r2 < 4; ++r2) {
            int idx = (R + quad * 4 + r2) * 64 + n * 16 + l15;
            fb0[idx] = (laA[n][r2] + qbra[r2]) * PSCALE;
            fb1[idx] = (laB[n][r2] + qbrb[r2]) * PSCALE;
        }
    }

    // promo rows 64..66
    if (tid < 192) {
        int u = tid >> 6, vv2 = tid & 63;
        int mm = u * 64 + vv2;
        int r_ = mm / 24, c_ = mm - r_ * 24;
        int c3 = c_ / 3, cp = c_ - c3 * 3;
        fb0[(64 + u) * 64 + vv2] =
            promoLDS[0][cp][c3] + promoLDS[0][3][c3] + patchLDS[0][r_][c3];
        fb1[(64 + u) * 64 + vv2] =
            promoLDS[1][cp][c3] + promoLDS[1][3][c3] + patchLDS[1][r_][c3];
    }

    __syncthreads();   // #3: fullbufs ready

    // ---------------- gather ------------------------------------------------
    {
        float* orow0 = out + (size_t)bat0 * NPOL;
        float* orow1 = out + (size_t)(bat0 + 1) * NPOL;
        int   idxv[8];
        float v0[8], v1[8];
        #pragma unroll
        for (int i = 0; i < 8; ++i) {
            int g = tid + i * 256;
            idxv[i] = (g < NPOL) ? gidx[g] : 0;
        }
        #pragma unroll
        for (int i = 0; i < 8; ++i) {
            v0[i] = fb0[idxv[i]];
            v1[i] = fb1[idxv[i]];
        }
        #pragma unroll
        for (int i = 0; i < 8; ++i) {
            int g = tid + i * 256;
            if (g < NPOL) {
                orow0[g] = v0[i];
                if (has1) orow1[g] = v1[i];
            }
        }
    }
}

// ---------------- fallback kernel (no-workspace path, R9 structure) ---------
__global__ __launch_bounds__(256, 2)
void policy_main(const float* __restrict__ x,
                 const float* __restrict__ w1,
                 const float* __restrict__ w2,
                 const float* __restrict__ w3,
                 const float* __restrict__ b1,
                 const float* __restrict__ b2,
                 const float* __restrict__ b3,
                 const float* __restrict__ w4,
                 const int*   __restrict__ gidx,
                 float* __restrict__ out,
                 int nbat) {
    __shared__ __align__(16) unsigned char u_lds[2 * 32768];
    __shared__ __align__(16) bf16_t qscr[4][2][16 * 40];
    __shared__ float promoLDS[2][4][8];
    __shared__ float patchLDS[2][8][8];

    const int tid  = threadIdx.x;
    const int lane = tid & 63;
    const int wv   = tid >> 6;
    const int quad = lane >> 4;
    const int l15  = lane & 15;
    const int R    = wv * 16;

    const int bat0 = blockIdx.x * 2;
    const bool has1 = (bat0 + 1) < nbat;
    const int bat1 = has1 ? bat0 + 1 : bat0;

    bf16x8 xaA[8], xaB[8];
    {
        const float* xr0 = x + ((size_t)bat0 * 64 + R + l15) * 256;
        const float* xr1 = x + ((size_t)bat1 * 64 + R + l15) * 256;
        #pragma unroll
        for (int t = 0; t < 8; ++t) {
            xaA[t] = cvt8(xr0 + t * 32 + quad * 8);
            xaB[t] = cvt8(xr1 + t * 32 + quad * 8);
        }
    }

    layer2b<false, true>(xaA, xaB, nullptr, w1, b1, u_lds, lane, quad, l15, R);
    bf16x8 oaA[8], oaB[8];
    #pragma unroll
    for (int t = 0; t < 8; ++t) {
        int off = ks_off(R + l15, t * 32 + quad * 8);
        oaA[t] = *(const bf16x8*)(u_lds + off);
        oaB[t] = *(const bf16x8*)(u_lds + 32768 + off);
    }

    layer2b<false, false>(oaA, oaB, nullptr, w3, b3, u_lds, lane, quad, l15, R);

    __syncthreads();

    f32x4 laA[4], laB[4];
    #pragma unroll
    for (int n = 0; n < 4; ++n) {
        laA[n] = (f32x4){0.f,0.f,0.f,0.f};
        laB[n] = (f32x4){0.f,0.f,0.f,0.f};
    }
    {
        bf16_t* qsA = &qscr[wv][0][0];
        bf16_t* qsB = &qscr[wv][1][0];
        bf16x8 wA[4], wB[4];
        #pragma unroll
        for (int t = 0; t < 4; ++t)
            wA[t] = wfrag<false>(nullptr, w2, 0, t, lane);

        #pragma unroll
        for (int t8 = 0; t8 < 8; ++t8) {
            const int n0 = 2 * t8, n1 = n0 + 1;
            #pragma unroll
            for (int t = 0; t < 4; ++t)
                wB[t] = wfrag<false>(nullptr, w2, n0, 4 + t, lane);
            {
                f32x4 cA0 = {0.f,0.f,0.f,0.f}, cA1 = {0.f,0.f,0.f,0.f};
                f32x4 cB0 = {0.f,0.f,0.f,0.f}, cB1 = {0.f,0.f,0.f,0.f};
                cA0 = MFMA(oaA[0], wA[0], cA0);  cB0 = MFMA(oaB[0], wA[0], cB0);
                cA1 = MFMA(oaA[1], wA[1], cA1);  cB1 = MFMA(oaB[1], wA[1], cB1);
                cA0 = MFMA(oaA[2], wA[2], cA0);  cB0 = MFMA(oaB[2], wA[2], cB0);
                cA1 = MFMA(oaA[3], wA[3], cA1);  cB1 = MFMA(oaB[3], wA[3], cB1);
                #pragma unroll
                for (int t = 0; t < 4; ++t)
                    wA[t] = wfrag<false>(nullptr, w2, n1, t, lane);
                cA0 = MFMA(oaA[4], wB[0], cA0);  cB0 = MFMA(oaB[4], wB[0], cB0);
                cA1 = MFMA(oaA[5], wB[1], cA1);  cB1 = MFMA(oaB[5], wB[1], cB1);
                cA0 = MFMA(oaA[6], wB[2], cA0);  cB0 = MFMA(oaB[6], wB[2], cB0);
                cA1 = MFMA(oaA[7], wB[3], cA1);  cB1 = MFMA(oaB[7], wB[3], cB1);
                f32x4 sA = cA0 + cA1, sB = cB0 + cB1;
                float bv = b2[n0 * 16 + l15];
                #pragma unroll
                for (int r2 = 0; r2 < 4; ++r2) {
                    int qo = (quad * 4 + r2) * 40 + l15;
                    qsA[qo] = (bf16_t)(sA[r2] + bv);
                    qsB[qo] = (bf16_t)(sB[r2] + bv);
                }
            }
            #pragma unroll
            for (int t = 0; t < 4; ++t)
                wB[t] = wfrag<false>(nullptr, w2, n1, 4 + t, lane);
            {
                f32x4 cA0 = {0.f,0.f,0.f,0.f}, cA1 = {0.f,0.f,0.f,0.f};
                f32x4 cB0 = {0.f,0.f,0.f,0.f}, cB1 = {0.f,0.f,0.f,0.f};
                cA0 = MFMA(oaA[0], wA[0], cA0);  cB0 = MFMA(oaB[0], wA[0], cB0);
                cA1 = MFMA(oaA[1], wA[1], cA1);  cB1 = MFMA(oaB[1], wA[1], cB1);
                cA0 = MFMA(oaA[2], wA[2], cA0);  cB0 = MFMA(oaB[2], wA[2], cB0);
                cA1 = MFMA(oaA[3], wA[3], cA1);  cB1 = MFMA(oaB[3], wA[3], cB1);
                if (t8 < 7) {
                    #pragma unroll
                    for (int t = 0; t < 4; ++t)
                        wA[t] = wfrag<false>(nullptr, w2, n0 + 2, t, lane);
                }
                cA0 = MFMA(oaA[4], wB[0], cA0);  cB0 = MFMA(oaB[4], wB[0], cB0);
                cA1 = MFMA(oaA[5], wB[1], cA1);  cB1 = MFMA(oaB[5], wB[1], cB1);
                cA0 = MFMA(oaA[6], wB[2], cA0);  cB0 = MFMA(oaB[6], wB[2], cB0);
                cA1 = MFMA(oaA[7], wB[3], cA1);  cB1 = MFMA(oaB[7], wB[3], cB1);
                f32x4 sA = cA0 + cA1, sB = cB0 + cB1;
                float bv = b2[n1 * 16 + l15];
                #pragma unroll
                for (int r2 = 0; r2 < 4; ++r2) {
                    int qo = (quad * 4 + r2) * 40 + 16 + l15;
                    qsA[qo] = (bf16_t)(sA[r2] + bv);
                    qsB[qo] = (bf16_t)(sB[r2] + bv);
                }
            }
            bf16x8 qaA = *(const bf16x8*)(qsA + l15 * 40 + quad * 8);
            bf16x8 qaB = *(const bf16x8*)(qsB + l15 * 40 + quad * 8);
            #pragma unroll
            for (int np = 0; np < 4; ++np) {
                int ko = ks_off(np * 16 + l15, t8 * 32 + quad * 8);
                bf16x8 kA = *(const bf16x8*)(u_lds + ko);
                bf16x8 kB = *(const bf16x8*)(u_lds + 32768 + ko);
                laA[np] = MFMA(qaA, kA, laA[np]);
                laB[np] = MFMA(qaB, kB, laB[np]);
            }
        }
    }

    {
        int s = lane >> 3, seg = lane & 7;
        const float* wrow = w4 + wv * 256;
        #pragma unroll
        for (int b = 0; b < 2; ++b) {
            const unsigned char* kb = u_lds + b * 32768;
            float p = 0.f;
            #pragma unroll
            for (int m = 0; m < 4; ++m) {
                bf16x8 kv = *(const bf16x8*)(kb + ks_off(56 + s, seg * 32 + m * 8));
                f32x4 wa = *(const f32x4*)(wrow + seg * 32 + m * 8);
                f32x4 wb = *(const f32x4*)(wrow + seg * 32 + m * 8 + 4);
                p += (float)kv[0] * wa[0] + (float)kv[1] * wa[1]
                   + (float)kv[2] * wa[2] + (float)kv[3] * wa[3]
                   + (float)kv[4] * wb[0] + (float)kv[5] * wb[1]
                   + (float)kv[6] * wb[2] + (float)kv[7] * wb[3];
            }
            p += __shfl_down(p, 4);
            p += __shfl_down(p, 2);
            p += __shfl_down(p, 1);
            if (seg == 0) promoLDS[b][wv][s] = p;
        }
    }

    if (wv == 3 && quad < 2 && l15 >= 8) {
        #pragma unroll
        for (int r2 = 0; r2 < 4; ++r2) {
            patchLDS[0][quad * 4 + r2][l15 - 8] = laA[3][r2] * PSCALE;
            patchLDS[1][quad * 4 + r2][l15 - 8] = laB[3][r2] * PSCALE;
        }
    }

    __syncthreads();

    float* fb0 = (float*)u_lds;
    float* fb1 = (float*)(u_lds + 32768);
    #pragma unroll
    for (int n = 0; n < 4; ++n) {
        #pragma unroll
        for (int r2 = 0; r2 < 4; ++r2) {
            int idx = (R + quad * 4 + r2) * 64 + n * 16 + l15;
            fb0[idx] = laA[n][r2] * PSCALE;
            fb1[idx] = laB[n][r2] * PSCALE;
        }
    }

    if (tid < 192) {
        int u = tid >> 6, vv2 = tid & 63;
        int mm = u * 64 + vv2;
        int r_ = mm / 24, c_ = mm - r_ * 24;
        int c3 = c_ / 3, cp = c_ - c3 * 3;
        fb0[(64 + u) * 64 + vv2] =
            promoLDS[0][cp][c3] + promoLDS[0][3][c3] + patchLDS[0][r_][c3];
        fb1[(64 + u) * 64 + vv2] =
            promoLDS[1][cp][c3] + promoLDS[1][3][c3] + patchLDS[1][r_][c3];
    }

    __syncthreads();

    {
        float* orow0 = out + (size_t)bat0 * NPOL;
        float* orow1 = out + (size_t)(bat0 + 1) * NPOL;
        int   idxv[8];
        float v0[8], v1[8];
        #pragma unroll
        for (int i = 0; i < 8; ++i) {
            int g = tid + i * 256;
            idxv[i] = (g < NPOL) ? gidx[g] : 0;
        }
        #pragma unroll
        for (int i = 0; i < 8; ++i) {
            v0[i] = fb0[idxv[i]];
            v1[i] = fb1[idxv[i]];
        }
        #pragma unroll
        for (int i = 0; i < 8; ++i) {
            int g = tid + i * 256;
            if (g < NPOL) {
                orow0[g] = v0[i];
                if (has1) orow1[g] = v1[i];
            }
        }
    }
}

extern "C" void kernel_launch(void* const* d_in, const int* in_sizes, int n_in,
                              void* d_out, int out_size, void* d_ws, size_t ws_size,
                              hipStream_t stream) {
    const float* x    = (const float*)d_in[0];
    const float* w1   = (const float*)d_in[1];
    const float* b1   = (const float*)d_in[2];
    const float* w2   = (const float*)d_in[3];
    const float* b2   = (const float*)d_in[4];
    const float* w3   = (const float*)d_in[5];
    const float* b3   = (const float*)d_in[6];
    const float* w4   = (const float*)d_in[7];
    const int*   gidx = (const int*)d_in[8];
    float* out = (float*)d_out;

    int nbat = in_sizes[0] / (64 * 256);        // 4096
    int nblk = (nbat + 1) / 2;
    // ws: wfA(128K) | wfM(128K) | flt(8K) | pscr(48K)
    const size_t ws_needed = 262144 + 8192 + 49152;

    if (ws_size >= ws_needed) {
        bf16_t* wfA = (bf16_t*)d_ws;
        bf16_t* wfM = wfA + 65536;
        float*  flt  = (float*)((char*)d_ws + 262144);
        float*  pscr = (float*)((char*)d_ws + 262144 + 8192);
        prep_all <<<520, 256, 0, stream>>>(w1, w2, w3, w4, b2, b3, wfA, wfM, pscr);
        prep_fold<<<1,   256, 0, stream>>>(w4, b2, b3, pscr, flt);
        policy_fused<<<nblk, 256, 0, stream>>>(
            x, wfA, wfM, flt, b1, gidx, out, nbat);
    } else {
        policy_main<<<nblk, 256, 0, stream>>>(
            x, w1, w2, w3, b1, b2, b3, w4, gidx, out, nbat);
    }
}